// Round 4
// baseline (2088.723 us; speedup 1.0000x reference)
//
#include <hip/hip_runtime.h>
#include <hip/hip_bf16.h>

using bf16 = __hip_bfloat16;

#define NIMG 8
#define NR 300
#define DIM 256
#define NHEAD 8
#define HD 32
#define SS 49
#define DDIM 64
#define FFD 2048
#define NCLS 80
#define MTOT (NIMG*NR)      // 2400
#define NFLAGS 32

typedef short short8 __attribute__((ext_vector_type(8)));
typedef float f32x4 __attribute__((ext_vector_type(4)));

// dual-dtype load: f32==1 -> buffer is float32, else bf16 (element index i)
__device__ inline float ldv(const void* p, long long i, int f32) {
  return f32 ? ((const float*)p)[i] : __bfloat162float(((const bf16*)p)[i]);
}

__device__ inline unsigned short f2bfu(float x) {
  bf16 b = __float2bfloat16(x);
  unsigned short u; __builtin_memcpy(&u, &b, 2); return u;
}
__device__ inline float bfu2f(unsigned short u) {
  bf16 b; __builtin_memcpy(&b, &u, 2); return __bfloat162float(b);
}

__device__ inline float wsum(float v) {
#pragma unroll
  for (int o = 32; o > 0; o >>= 1) v += __shfl_xor(v, o, 64);
  return v;
}
__device__ inline float wmaxf(float v) {
#pragma unroll
  for (int o = 32; o > 0; o >>= 1) v = fmaxf(v, __shfl_xor(v, o, 64));
  return v;
}
__device__ inline float bsum(float v, float* s4) {
  v = wsum(v);
  int w = threadIdx.x >> 6;
  if ((threadIdx.x & 63) == 0) s4[w] = v;
  __syncthreads();
  float r = s4[0] + s4[1] + s4[2] + s4[3];
  __syncthreads();
  return r;
}

// ---------------- diagnostics ----------------
__global__ __launch_bounds__(64) void zero_flags_kernel(int* flags) {
  if (threadIdx.x < NFLAGS) flags[threadIdx.x] = 0;
}
// w_qkv ~ N(0,1)*0.02: as bf16 |v|<1; f32 data misread as bf16 has huge/NaN values.
__global__ __launch_bounds__(256) void detect_dtype_kernel(const void* __restrict__ p,
                                                           long long n,
                                                           int* __restrict__ flags) {
  long long i = (long long)blockIdx.x*256 + threadIdx.x;
  long long stride = (long long)gridDim.x*256;
  int f32 = 0;
  for (; i < n; i += stride) {
    float v = __bfloat162float(((const bf16*)p)[i]);
    if (!(fabsf(v) <= 1.0e20f)) { f32 = 1; break; }
  }
  if (f32) atomicOr(&flags[0], 1);
}

// ---------------- prep ----------------
__global__ __launch_bounds__(256) void prep_kernel(const void* __restrict__ pro,
                                                   const void* __restrict__ query,
                                                   float* __restrict__ pf0,
                                                   float* __restrict__ qk,
                                                   const int* __restrict__ flags) {
  int f32 = flags[0];
  int i = blockIdx.x*256 + threadIdx.x;
  float p = ldv(pro, i, f32);
  pf0[i] = p;
  qk[i] = p + ldv(query, i, f32);
}

// ---------------- split fp32 -> (bf16 hi, bf16 lo) ----------------
__global__ __launch_bounds__(256) void split_kernel(const float* __restrict__ x,
                                                    unsigned short* __restrict__ hi,
                                                    unsigned short* __restrict__ lo,
                                                    long long n4) {
  long long q = (long long)blockIdx.x*256 + threadIdx.x;
  if (q >= n4) return;
  long long i = q*4;
  float4 v = *(const float4*)(x + i);
  float vv[4] = {v.x, v.y, v.z, v.w};
  unsigned short h[4], l[4];
#pragma unroll
  for (int j = 0; j < 4; ++j) {
    h[j] = f2bfu(vv[j]);
    l[j] = f2bfu(vv[j] - bfu2f(h[j]));
  }
  uint2 ph = make_uint2((unsigned)h[0] | ((unsigned)h[1]<<16),
                        (unsigned)h[2] | ((unsigned)h[3]<<16));
  uint2 pl = make_uint2((unsigned)l[0] | ((unsigned)l[1]<<16),
                        (unsigned)l[2] | ((unsigned)l[3]<<16));
  *(uint2*)(hi + i) = ph;
  *(uint2*)(lo + i) = pl;
}

// ---------------- MFMA GEMM: C[M,N] = (Ahi+Alo)[M,K] * W[N,K]^T + bias ----------------
// A pre-split into bf16 hi/lo (error ~2^-17). Weights: bf16 -> exact (2 MFMA terms);
// fp32 -> split in staging, 3rd term a_hi*w_lo added.
// Tile 128x64, BK=32, 4 waves each 32(M)x64(N) = 2x4 16x16 frags.
// Chi/Clo non-null: write output as bf16 hi/lo pair (not valid with splitk).
#define GBM 128
#define GBN 64
#define GBK 32
__global__ __launch_bounds__(256) void gemm_mfma_k(
    const unsigned short* __restrict__ Ahi, const unsigned short* __restrict__ Alo,
    const void* __restrict__ Wt, long long woff,
    const void* __restrict__ bias, long long boff,
    float* __restrict__ C,
    unsigned short* __restrict__ Chi, unsigned short* __restrict__ Clo,
    int M, int Nn, int K, int relu, int kit, int splitk,
    const int* __restrict__ flags) {
  int f32 = flags[0];
  __shared__ __align__(16) unsigned short Ah[GBM][40];
  __shared__ __align__(16) unsigned short Al[GBM][40];
  __shared__ __align__(16) unsigned short Bh[GBN][40];
  __shared__ __align__(16) unsigned short Bl[GBN][40];
  int tid = threadIdx.x;
  int lane = tid & 63, wid = tid >> 6;
  int wm = wid * 32;
  int m0 = blockIdx.x*GBM, n0 = blockIdx.y*GBN;
  int row = lane & 15, kb = (lane >> 4) * 8;
  int kbeg = 0, kend = K;
  if (splitk) { kbeg = blockIdx.z*kit*GBK; kend = kbeg + kit*GBK; if (kend > K) kend = K; }
  f32x4 zero = {0.f, 0.f, 0.f, 0.f};
  f32x4 acc[2][4];
#pragma unroll
  for (int i = 0; i < 2; ++i)
#pragma unroll
    for (int j = 0; j < 4; ++j) acc[i][j] = zero;
  int sr = tid >> 2, kq = (tid & 3) * 8;
  for (int k0 = kbeg; k0 < kend; k0 += GBK) {
#pragma unroll
    for (int p = 0; p < 2; ++p) {
      int r = sr + p*64;
      int gm = m0 + r;
      uint4 h = {0,0,0,0}, l = {0,0,0,0};
      if (gm < M) {
        size_t e = (size_t)gm*K + k0 + kq;
        h = *(const uint4*)(Ahi + e);
        l = *(const uint4*)(Alo + e);
      }
      *(uint4*)&Ah[r][kq] = h;
      *(uint4*)&Al[r][kq] = l;
    }
    {
      int gn = n0 + sr;
      if (!f32) {
        uint4 h = {0,0,0,0};
        if (gn < Nn)
          h = *(const uint4*)((const unsigned short*)Wt + woff + (size_t)gn*K + k0 + kq);
        *(uint4*)&Bh[sr][kq] = h;
      } else {
        float v[8] = {0.f,0.f,0.f,0.f,0.f,0.f,0.f,0.f};
        if (gn < Nn) {
          const float* wp = (const float*)Wt + woff + (size_t)gn*K + k0 + kq;
          float4 u0 = *(const float4*)wp;
          float4 u1 = *(const float4*)(wp + 4);
          v[0]=u0.x; v[1]=u0.y; v[2]=u0.z; v[3]=u0.w;
          v[4]=u1.x; v[5]=u1.y; v[6]=u1.z; v[7]=u1.w;
        }
        unsigned short h[8], l[8];
#pragma unroll
        for (int j = 0; j < 8; ++j) {
          h[j] = f2bfu(v[j]);
          l[j] = f2bfu(v[j] - bfu2f(h[j]));
        }
        uint4 ph = {(unsigned)h[0]|((unsigned)h[1]<<16), (unsigned)h[2]|((unsigned)h[3]<<16),
                    (unsigned)h[4]|((unsigned)h[5]<<16), (unsigned)h[6]|((unsigned)h[7]<<16)};
        uint4 pl = {(unsigned)l[0]|((unsigned)l[1]<<16), (unsigned)l[2]|((unsigned)l[3]<<16),
                    (unsigned)l[4]|((unsigned)l[5]<<16), (unsigned)l[6]|((unsigned)l[7]<<16)};
        *(uint4*)&Bh[sr][kq] = ph;
        *(uint4*)&Bl[sr][kq] = pl;
      }
    }
    __syncthreads();
    short8 ah[2], al[2], bh[4];
#pragma unroll
    for (int fm = 0; fm < 2; ++fm) {
      ah[fm] = *(const short8*)&Ah[wm + fm*16 + row][kb];
      al[fm] = *(const short8*)&Al[wm + fm*16 + row][kb];
    }
#pragma unroll
    for (int fn = 0; fn < 4; ++fn) bh[fn] = *(const short8*)&Bh[fn*16 + row][kb];
#pragma unroll
    for (int fm = 0; fm < 2; ++fm)
#pragma unroll
      for (int fn = 0; fn < 4; ++fn) {
        acc[fm][fn] = __builtin_amdgcn_mfma_f32_16x16x32_bf16(ah[fm], bh[fn], acc[fm][fn], 0, 0, 0);
        acc[fm][fn] = __builtin_amdgcn_mfma_f32_16x16x32_bf16(al[fm], bh[fn], acc[fm][fn], 0, 0, 0);
      }
    if (f32) {
      short8 bl[4];
#pragma unroll
      for (int fn = 0; fn < 4; ++fn) bl[fn] = *(const short8*)&Bl[fn*16 + row][kb];
#pragma unroll
      for (int fm = 0; fm < 2; ++fm)
#pragma unroll
        for (int fn = 0; fn < 4; ++fn)
          acc[fm][fn] = __builtin_amdgcn_mfma_f32_16x16x32_bf16(ah[fm], bl[fn], acc[fm][fn], 0, 0, 0);
    }
    __syncthreads();
  }
  // epilogue: C/D layout col = lane&15, row = (lane>>4)*4 + reg
#pragma unroll
  for (int fm = 0; fm < 2; ++fm) {
    int rb = m0 + wm + fm*16 + (lane >> 4)*4;
#pragma unroll
    for (int fn = 0; fn < 4; ++fn) {
      int gc = n0 + fn*16 + row;
      if (gc >= Nn) continue;
#pragma unroll
      for (int j = 0; j < 4; ++j) {
        int gm = rb + j;
        if (gm >= M) continue;
        float v = acc[fm][fn][j];
        if (splitk) {
          atomicAdd(&C[(size_t)gm*Nn + gc], v);
        } else {
          if (bias) v += ldv(bias, boff + gc, f32);
          if (relu) v = fmaxf(v, 0.f);
          if (Chi) {
            unsigned short h = f2bfu(v);
            unsigned short l = f2bfu(v - bfu2f(h));
            size_t o = (size_t)gm*Nn + gc;
            Chi[o] = h; Clo[o] = l;
          } else {
            C[(size_t)gm*Nn + gc] = v;
          }
        }
      }
    }
  }
}

// C[i] = bias[i % Nn] (or 0) — init target for split-K accumulation
__global__ __launch_bounds__(256) void init_bias_kernel(float* __restrict__ C,
                                                        const void* __restrict__ bias,
                                                        long long boff, int n, int Nn,
                                                        const int* __restrict__ flags) {
  int f32 = flags[0];
  int i = blockIdx.x*256 + threadIdx.x;
  if (i < n) C[i] = bias ? ldv(bias, boff + (i % Nn), f32) : 0.f;
}

// ---------------- fused masked MHA ----------------
__global__ __launch_bounds__(256) void attn_kernel(const float* __restrict__ qp,
                                                   const float* __restrict__ kp,
                                                   const float* __restrict__ vp,
                                                   const void* __restrict__ bboxes,
                                                   const void* __restrict__ mask,
                                                   float* __restrict__ ctx,
                                                   const int* __restrict__ flags) {
  int f32 = flags[0];
  int nq = blockIdx.x;
  int n = nq / NR, q = nq % NR;
  __shared__ float qv[DIM];
  __shared__ float sc[NHEAD*NR];
  int t = threadIdx.x;
  qv[t] = qp[(size_t)nq*DIM + t];
  __syncthreads();
  float mq = ldv(mask, nq, f32);
  float qx0 = ldv(bboxes, (long long)nq*4+0, f32);
  float qy0 = ldv(bboxes, (long long)nq*4+1, f32);
  float qx1 = ldv(bboxes, (long long)nq*4+2, f32);
  float qy1 = ldv(bboxes, (long long)nq*4+3, f32);
  float areaq = (qx1-qx0)*(qy1-qy0);
  for (int idx = t; idx < NHEAD*NR; idx += 256) {
    int h = idx / NR, k = idx % NR;
    const float* kr = kp + ((size_t)n*NR + k)*DIM + h*HD;
    const float* qh = qv + h*HD;
    float s = 0.f;
#pragma unroll
    for (int d = 0; d < HD; ++d) s += qh[d]*kr[d];
    s *= 0.17677669529663687f;   // 1/sqrt(32)
    long long bk = (long long)(n*NR + k)*4;
    float kx0 = ldv(bboxes, bk+0, f32);
    float ky0 = ldv(bboxes, bk+1, f32);
    float kx1 = ldv(bboxes, bk+2, f32);
    float ky1 = ldv(bboxes, bk+3, f32);
    float areak = (kx1-kx0)*(ky1-ky0);
    float lx = fmaxf(qx0, kx0), ly = fmaxf(qy0, ky0);
    float rx = fminf(qx1, kx1), ry = fminf(qy1, ky1);
    float iw = fmaxf(rx-lx, 0.f), ih = fmaxf(ry-ly, 0.f);
    float inter = iw*ih;
    float uni = areaq + areak - inter;
    float iou = inter / fmaxf(uni, 1e-9f);
    float mk = ldv(mask, n*NR + k, f32);
    float am = (iou < 0.5f ? 1.f : 0.f)*mq*mk + ((q == k) ? (1.f - mq) : 0.f);
    if (am > 0.f) s = -1e9f;
    sc[idx] = s;
  }
  __syncthreads();
  int wv = t >> 6, lane = t & 63;
  for (int h = wv*2; h < wv*2 + 2; ++h) {
    float mx = -3.4e38f;
    for (int k = lane; k < NR; k += 64) mx = fmaxf(mx, sc[h*NR + k]);
    mx = wmaxf(mx);
    float sum = 0.f;
    for (int k = lane; k < NR; k += 64) {
      float e = expf(sc[h*NR + k] - mx);
      sc[h*NR + k] = e;
      sum += e;
    }
    sum = wsum(sum);
    float inv = 1.f / sum;
    for (int k = lane; k < NR; k += 64) sc[h*NR + k] *= inv;
  }
  __syncthreads();
  int h = t >> 5, d = t & 31;
  float acc = 0.f;
  const float* vb = vp + (size_t)n*NR*DIM + h*HD + d;
  for (int k = 0; k < NR; ++k) acc += sc[h*NR + k] * vb[(size_t)k*DIM];
  ctx[(size_t)nq*DIM + t] = acc;
}

// ---------------- norm1 ----------------
__global__ __launch_bounds__(256) void norm1_kernel(const float* __restrict__ pf0,
                                                    const float* __restrict__ tgt2,
                                                    const void* __restrict__ mask,
                                                    float* __restrict__ pf1,
                                                    const int* __restrict__ flags) {
  int f32 = flags[0];
  int r = blockIdx.x, t = threadIdx.x;
  __shared__ float s4[4];
  float x = pf0[(size_t)r*DIM + t] + tgt2[(size_t)r*DIM + t];
  float mean = bsum(x, s4) * (1.f/DIM);
  float df = x - mean;
  float var = bsum(df*df, s4) * (1.f/DIM);
  float y = df * rsqrtf(var + 1e-5f);
  pf1[(size_t)r*DIM + t] = y * ldv(mask, r, f32);
}

// ---------------- fused DynamicConv: per-instance dyn1 + LN + relu + dyn2 + LN + relu ----
// One block per instance row r. Reads p1,p2 exactly once; roi staged in LDS once.
// Output f2 written directly as bf16 hi/lo split (feeds dyn_out GEMM).
#define DROW 260
#define F1ROW 68
__global__ __launch_bounds__(256) void dyn_fused_kernel(const void* __restrict__ roi,
                                                        const float* __restrict__ P,
                                                        unsigned short* __restrict__ f2hi,
                                                        unsigned short* __restrict__ f2lo,
                                                        int r0,
                                                        const int* __restrict__ flags) {
  int f32 = flags[0];
  int ci = blockIdx.x;
  int r = r0 + ci;
  __shared__ float S[SS*DROW];      // roi [49][256] (stage1), then S2 [49][256]
  __shared__ float F1[SS*F1ROW];    // f1 [49][64]
  int tid = threadIdx.x;
  int lane = tid & 63, sg = tid >> 6;
  // stage roi rows (coalesced)
  for (int s = 0; s < SS; ++s)
    S[s*DROW + tid] = ldv(roi, ((long long)s*MTOT + r)*DIM + tid, f32);
  __syncthreads();
  // stage 1: S1[s][e] = sum_d roi[s][d]*p1[d][e]; thread (sg, e=lane) owns s = sg+4j
  const float* p1 = P + (size_t)ci*(2*DIM*DDIM);
  float acc1[13];
#pragma unroll
  for (int j = 0; j < 13; ++j) acc1[j] = 0.f;
  for (int d = 0; d < DIM; ++d) {
    float pv = p1[d*DDIM + lane];          // coalesced across lanes
#pragma unroll
    for (int j = 0; j < 13; ++j) {
      int s = sg + 4*j;
      if (s < SS) acc1[j] += S[s*DROW + d] * pv;   // LDS broadcast
    }
  }
#pragma unroll
  for (int j = 0; j < 13; ++j) {
    int s = sg + 4*j;
    if (s < SS) F1[s*F1ROW + lane] = acc1[j];
  }
  __syncthreads();
  // LN over e (=64) per row s, + relu; wave sg handles rows sg+4j
  for (int j = 0; j < 13; ++j) {
    int s = sg + 4*j;
    if (s >= SS) break;
    float x = F1[s*F1ROW + lane];
    float m = wsum(x) * (1.f/DDIM);
    float df = x - m;
    float v = wsum(df*df) * (1.f/DDIM);
    F1[s*F1ROW + lane] = fmaxf(df * rsqrtf(v + 1e-5f), 0.f);
  }
  __syncthreads();
  // stage 2: S2[s][d] = sum_e f1[s][e]*p2[e][d]; thread d = tid owns all 49 s
  const float* p2 = p1 + DIM*DDIM;
  float acc2[SS];
#pragma unroll
  for (int s = 0; s < SS; ++s) acc2[s] = 0.f;
  for (int e = 0; e < DDIM; ++e) {
    float pv = p2[e*DIM + tid];            // coalesced across block
#pragma unroll
    for (int s = 0; s < SS; ++s) acc2[s] += F1[s*F1ROW + e] * pv;  // LDS broadcast
  }
  __syncthreads();
#pragma unroll
  for (int s = 0; s < SS; ++s) S[s*DROW + tid] = acc2[s];
  __syncthreads();
  // LN over d (=256) per row s, + relu, + bf16 hi/lo split write
  for (int j = 0; j < 13; ++j) {
    int s = sg + 4*j;
    if (s >= SS) break;
    float4 x = *(float4*)&S[s*DROW + lane*4];
    float sm = x.x + x.y + x.z + x.w;
    float m = wsum(sm) * (1.f/DIM);
    float dx[4] = {x.x-m, x.y-m, x.z-m, x.w-m};
    float vv = dx[0]*dx[0] + dx[1]*dx[1] + dx[2]*dx[2] + dx[3]*dx[3];
    float var = wsum(vv) * (1.f/DIM);
    float rs = rsqrtf(var + 1e-5f);
    unsigned short h[4], l[4];
#pragma unroll
    for (int q = 0; q < 4; ++q) {
      float y = fmaxf(dx[q]*rs, 0.f);
      h[q] = f2bfu(y);
      l[q] = f2bfu(y - bfu2f(h[q]));
    }
    size_t o = ((size_t)ci*SS + s)*DIM + lane*4;
    *(uint2*)(f2hi + o) = make_uint2((unsigned)h[0]|((unsigned)h[1]<<16),
                                     (unsigned)h[2]|((unsigned)h[3]<<16));
    *(uint2*)(f2lo + o) = make_uint2((unsigned)l[0]|((unsigned)l[1]<<16),
                                     (unsigned)l[2]|((unsigned)l[3]<<16));
  }
}

// ---------------- normdyn ----------------
__global__ __launch_bounds__(256) void normdyn_kernel(const float* __restrict__ g,
                                                      const float* __restrict__ pf1,
                                                      float* __restrict__ pfB) {
  int r = blockIdx.x, t = threadIdx.x;
  __shared__ float s4[4];
  float x = g[(size_t)r*DIM + t];
  float mean = bsum(x, s4)*(1.f/DIM);
  float df = x - mean;
  float var = bsum(df*df, s4)*(1.f/DIM);
  float y = fmaxf(df*rsqrtf(var+1e-5f), 0.f);
  float x2 = pf1[(size_t)r*DIM + t] + y;
  float mean2 = bsum(x2, s4)*(1.f/DIM);
  float df2 = x2 - mean2;
  float var2 = bsum(df2*df2, s4)*(1.f/DIM);
  pfB[(size_t)r*DIM + t] = df2*rsqrtf(var2+1e-5f);
}

// ---------------- norm3 ----------------
__global__ __launch_bounds__(256) void norm3_kernel(const float* __restrict__ pfB,
                                                    const float* __restrict__ t2,
                                                    const void* __restrict__ mask,
                                                    float* __restrict__ fc,
                                                    const int* __restrict__ flags) {
  int f32 = flags[0];
  int r = blockIdx.x, t = threadIdx.x;
  __shared__ float s4[4];
  float x = pfB[(size_t)r*DIM + t] + t2[(size_t)r*DIM + t];
  float mean = bsum(x, s4)*(1.f/DIM);
  float df = x - mean;
  float var = bsum(df*df, s4)*(1.f/DIM);
  float y = df*rsqrtf(var+1e-5f);
  fc[(size_t)r*DIM + t] = y * ldv(mask, r, f32);
}

// ---------------- lncls ----------------
__global__ __launch_bounds__(256) void lncls_kernel(const float* __restrict__ g,
                                                    float* __restrict__ out) {
  int r = blockIdx.x, t = threadIdx.x;
  __shared__ float s4[4];
  float x = g[(size_t)r*DIM + t];
  float mean = bsum(x, s4)*(1.f/DIM);
  float df = x - mean;
  float var = bsum(df*df, s4)*(1.f/DIM);
  out[(size_t)r*DIM + t] = fmaxf(df*rsqrtf(var+1e-5f), 0.f);
}

// ---------------- final: sanitize + diag code; output dtype per flags[0] ----------------
__global__ __launch_bounds__(256) void final_kernel(const float* __restrict__ logf,
                                                    const int* __restrict__ flags,
                                                    void* __restrict__ out, int n) {
  int f32 = flags[0];
  int i = blockIdx.x*256 + threadIdx.x;
  if (i < n) {
    float v = logf[i];
    if (!(fabsf(v) <= 3.0e38f)) v = 0.f;
    if (i == 0) {
      int code = 0;
      for (int s = NFLAGS - 1; s >= 1; --s) if (flags[s]) code = 100 + 4*s;
      if (code) v = (float)code;
    }
    if (f32) ((float*)out)[i] = v;
    else ((bf16*)out)[i] = __float2bfloat16(v);
  }
}

extern "C" void kernel_launch(void* const* d_in, const int* in_sizes, int n_in,
                              void* d_out, int out_size, void* d_ws, size_t ws_size,
                              hipStream_t stream) {
  const void* bboxes     = d_in[0];
  const void* pro        = d_in[1];
  const void* roi        = d_in[2];
  const void* query      = d_in[3];
  const void* mask       = d_in[4];
  const void* w_qkv      = d_in[5];
  const void* b_qkv      = d_in[6];
  const void* w_attn_out = d_in[7];
  const void* b_attn_out = d_in[8];
  const void* w_dyn      = d_in[9];
  const void* b_dyn      = d_in[10];
  const void* w_dyn_out  = d_in[11];
  const void* b_dyn_out  = d_in[12];
  const void* w_ff1      = d_in[13];
  const void* b_ff1      = d_in[14];
  const void* w_ff2      = d_in[15];
  const void* b_ff2      = d_in[16];
  const void* w_cls      = d_in[17];
  const void* w_logits   = d_in[18];
  const void* b_logits   = d_in[19];
  (void)in_sizes; (void)n_in; (void)out_size;

  const size_t RD = (size_t)MTOT*DIM;

  // ---- workspace tiers: dyn chunk CHN, ffn chunk FH, split-buffer SPL elems ----
  const size_t DYNROW = (size_t)2*DIM*DDIM;   // Pc only (f1/f2 now LDS/split-buf)
  size_t wsf = ws_size / sizeof(float);
  size_t fixedf = 5*RD + (size_t)MTOT*NCLS + 256;
  auto spl_of = [&](size_t chn, size_t fh) {
    size_t a = chn*(size_t)SS*DIM, b = fh*(size_t)FFD;
    size_t m = a > b ? a : b; return m > RD ? m : RD;
  };
  auto need = [&](size_t chn, size_t fh) {
    return fixedf + chn*DYNROW + fh*FFD + spl_of(chn, fh);
  };
  int CHN = 64, FH = 300;
  if (wsf >= need(2400, MTOT))      { CHN = 2400; FH = MTOT; }
  else if (wsf >= need(1200, MTOT)) { CHN = 1200; FH = MTOT; }
  else if (wsf >= need(600, MTOT))  { CHN = 600;  FH = MTOT; }
  else if (wsf >= need(300, MTOT))  { CHN = 300;  FH = MTOT; }
  else if (wsf >= need(150, 300))   { CHN = 150;  FH = 300;  }
  const size_t SPL = spl_of(CHN, FH);

  float* Wsp = (float*)d_ws;
  size_t off = 0;
  auto alloc = [&](size_t n) { float* p = Wsp + off; off += n; return p; };
  float* A = alloc(RD);
  float* B = alloc(RD);
  float* C = alloc(RD);
  float* D = alloc(RD);
  float* E = alloc(RD);
  float* logf = alloc((size_t)MTOT*NCLS);
  float* ffh = alloc((size_t)FH*FFD);          // holds bf16 hi/lo pair for ffn hidden
  float* Pc  = alloc((size_t)CHN*2*DIM*DDIM);
  unsigned short* Ahi = (unsigned short*)alloc(SPL/2 + 8);
  unsigned short* Alo = (unsigned short*)alloc(SPL/2 + 8);
  int* flags = (int*)(Wsp + off);
  unsigned short* ffhi = (unsigned short*)ffh;
  unsigned short* fflo = ffhi + (size_t)FH*FFD;

  dim3 b256(256);
  auto split = [&](const float* x, long long n) {
    long long n4 = n/4;
    split_kernel<<<(int)((n4 + 255)/256), b256, 0, stream>>>(x, Ahi, Alo, n4);
  };
  // MFMA GEMM launcher; split-K via atomicAdd when grid starves; optional hi/lo output.
  auto gemm_full = [&](const unsigned short* Ah_, const unsigned short* Al_,
                       const void* Wm, long long woff,
                       const void* bias, long long boff, float* Cm,
                       unsigned short* Chi, unsigned short* Clo,
                       int M, int Nn, int K, int relu) {
    int gm = (M + GBM - 1)/GBM;
    int gn = (Nn + GBN - 1)/GBN;
    int ntiles = K / GBK;
    int ks = 1;
    if (!relu && !Chi && gm*gn < 512) {
      ks = (768 + gm*gn - 1)/(gm*gn);
      if (ks > ntiles) ks = ntiles;
    }
    int kit = (ntiles + ks - 1)/ks;
    ks = (ntiles + kit - 1)/kit;
    if (ks > 1) {
      int n = M*Nn;
      init_bias_kernel<<<(n + 255)/256, b256, 0, stream>>>(Cm, bias, boff, n, Nn, flags);
      gemm_mfma_k<<<dim3(gm, gn, ks), b256, 0, stream>>>(Ah_, Al_, Wm, woff, nullptr, 0,
                                                         Cm, nullptr, nullptr,
                                                         M, Nn, K, relu, kit, 1, flags);
    } else {
      gemm_mfma_k<<<dim3(gm, gn, 1), b256, 0, stream>>>(Ah_, Al_, Wm, woff, bias, boff,
                                                        Cm, Chi, Clo,
                                                        M, Nn, K, relu, kit, 0, flags);
    }
  };
  auto gemm = [&](const unsigned short* Ah_, const unsigned short* Al_,
                  const void* Wm, long long woff,
                  const void* bias, long long boff, float* Cm,
                  int M, int Nn, int K, int relu) {
    gemm_full(Ah_, Al_, Wm, woff, bias, boff, Cm, nullptr, nullptr, M, Nn, K, relu);
  };

  zero_flags_kernel<<<1, 64, 0, stream>>>(flags);
  detect_dtype_kernel<<<256, b256, 0, stream>>>(w_qkv, 3LL*DIM*DIM, flags);

  prep_kernel<<<MTOT, b256, 0, stream>>>(pro, query, A, B, flags);  // A=pf0 B=qk
  split(B, RD);
  gemm(Ahi, Alo, w_qkv, 0,                  b_qkv, 0,     C, MTOT, DIM, DIM, 0);  // C=qp
  gemm(Ahi, Alo, w_qkv, (long long)DIM*DIM, b_qkv, DIM,   D, MTOT, DIM, DIM, 0);  // D=kp
  split(A, RD);
  gemm(Ahi, Alo, w_qkv, 2LL*DIM*DIM,        b_qkv, 2*DIM, E, MTOT, DIM, DIM, 0);  // E=vp
  attn_kernel<<<MTOT, b256, 0, stream>>>(C, D, E, bboxes, mask, B, flags);        // B=ctx
  split(B, RD);
  gemm(Ahi, Alo, w_attn_out, 0, b_attn_out, 0, C, MTOT, DIM, DIM, 0);             // C=tgt2
  norm1_kernel<<<MTOT, b256, 0, stream>>>(A, C, mask, D, flags);                  // D=pf1

  for (int r0 = 0; r0 < MTOT; r0 += CHN) {
    int m = MTOT - r0 < CHN ? MTOT - r0 : CHN;
    split(D + (size_t)r0*DIM, (long long)m*DIM);
    gemm(Ahi, Alo, w_dyn, 0, b_dyn, 0, Pc, m, 2*DIM*DDIM, DIM, 0);
    // fused dyn1+LN+relu+dyn2+LN+relu; writes f2 hi/lo into Ahi/Alo (P-GEMM done reading)
    dyn_fused_kernel<<<m, b256, 0, stream>>>(roi, Pc, Ahi, Alo, r0, flags);
    gemm(Ahi, Alo, w_dyn_out, 0, b_dyn_out, 0, E + (size_t)r0*DIM,
         m, DIM, SS*DIM, 0);                                                      // E=gdyn
  }
  normdyn_kernel<<<MTOT, b256, 0, stream>>>(E, D, A);                             // A=pfB

  for (int r0 = 0; r0 < MTOT; r0 += FH) {
    int m = MTOT - r0 < FH ? MTOT - r0 : FH;
    split(A + (size_t)r0*DIM, (long long)m*DIM);
    gemm_full(Ahi, Alo, w_ff1, 0, b_ff1, 0, nullptr, ffhi, fflo, m, FFD, DIM, 1); // hid hi/lo
    gemm(ffhi, fflo, w_ff2, 0, b_ff2, 0, B + (size_t)r0*DIM, m, DIM, FFD, 0);     // B=t2
  }
  norm3_kernel<<<MTOT, b256, 0, stream>>>(A, B, mask, C, flags);                  // C=fcb

  split(C, RD);
  gemm(Ahi, Alo, w_cls, 0, nullptr, 0, D, MTOT, DIM, DIM, 0);                     // D=clsg
  lncls_kernel<<<MTOT, b256, 0, stream>>>(D, E);                                  // E=clsf
  split(E, RD);
  gemm(Ahi, Alo, w_logits, 0, b_logits, 0, logf, MTOT, NCLS, DIM, 0);

  final_kernel<<<((MTOT*NCLS)+255)/256, b256, 0, stream>>>(logf, flags, d_out, MTOT*NCLS);
}

// Round 5
// 1364.899 us; speedup vs baseline: 1.5303x; 1.5303x over previous
//
#include <hip/hip_runtime.h>
#include <hip/hip_bf16.h>

using bf16 = __hip_bfloat16;

#define NIMG 8
#define NR 300
#define DIM 256
#define NHEAD 8
#define HD 32
#define SS 49
#define DDIM 64
#define FFD 2048
#define NCLS 80
#define MTOT (NIMG*NR)      // 2400
#define NFLAGS 32

typedef short short8 __attribute__((ext_vector_type(8)));
typedef float f32x4 __attribute__((ext_vector_type(4)));

// dual-dtype load: f32==1 -> buffer is float32, else bf16 (element index i)
__device__ inline float ldv(const void* p, long long i, int f32) {
  return f32 ? ((const float*)p)[i] : __bfloat162float(((const bf16*)p)[i]);
}

__device__ inline unsigned short f2bfu(float x) {
  bf16 b = __float2bfloat16(x);
  unsigned short u; __builtin_memcpy(&u, &b, 2); return u;
}
__device__ inline float bfu2f(unsigned short u) {
  bf16 b; __builtin_memcpy(&b, &u, 2); return __bfloat162float(b);
}

// weight-row permutation for the dyn P-GEMM: output col n (permuted layout
// p1T[e][d] then p2T[d][e]) <- original param row index.
__device__ inline int dynperm(int n) {
  if (n < DIM*DDIM) { int e = n >> 8, d = n & 255; return d*DDIM + e; }
  int q = n - DIM*DDIM; int d = q >> 6, e = q & 63; return DIM*DDIM + e*DIM + d;
}

__device__ inline float wsum(float v) {
#pragma unroll
  for (int o = 32; o > 0; o >>= 1) v += __shfl_xor(v, o, 64);
  return v;
}
__device__ inline float wmaxf(float v) {
#pragma unroll
  for (int o = 32; o > 0; o >>= 1) v = fmaxf(v, __shfl_xor(v, o, 64));
  return v;
}
__device__ inline float bsum(float v, float* s4) {
  v = wsum(v);
  int w = threadIdx.x >> 6;
  if ((threadIdx.x & 63) == 0) s4[w] = v;
  __syncthreads();
  float r = s4[0] + s4[1] + s4[2] + s4[3];
  __syncthreads();
  return r;
}

// ---------------- diagnostics ----------------
__global__ __launch_bounds__(64) void zero_flags_kernel(int* flags) {
  if (threadIdx.x < NFLAGS) flags[threadIdx.x] = 0;
}
__global__ __launch_bounds__(256) void detect_dtype_kernel(const void* __restrict__ p,
                                                           long long n,
                                                           int* __restrict__ flags) {
  long long i = (long long)blockIdx.x*256 + threadIdx.x;
  long long stride = (long long)gridDim.x*256;
  int f32 = 0;
  for (; i < n; i += stride) {
    float v = __bfloat162float(((const bf16*)p)[i]);
    if (!(fabsf(v) <= 1.0e20f)) { f32 = 1; break; }
  }
  if (f32) atomicOr(&flags[0], 1);
}

// ---------------- prep ----------------
__global__ __launch_bounds__(256) void prep_kernel(const void* __restrict__ pro,
                                                   const void* __restrict__ query,
                                                   float* __restrict__ pf0,
                                                   float* __restrict__ qk,
                                                   const int* __restrict__ flags) {
  int f32 = flags[0];
  int i = blockIdx.x*256 + threadIdx.x;
  float p = ldv(pro, i, f32);
  pf0[i] = p;
  qk[i] = p + ldv(query, i, f32);
}

// ---------------- split fp32 -> (bf16 hi, bf16 lo) ----------------
__global__ __launch_bounds__(256) void split_kernel(const float* __restrict__ x,
                                                    unsigned short* __restrict__ hi,
                                                    unsigned short* __restrict__ lo,
                                                    long long n4) {
  long long q = (long long)blockIdx.x*256 + threadIdx.x;
  if (q >= n4) return;
  long long i = q*4;
  float4 v = *(const float4*)(x + i);
  float vv[4] = {v.x, v.y, v.z, v.w};
  unsigned short h[4], l[4];
#pragma unroll
  for (int j = 0; j < 4; ++j) {
    h[j] = f2bfu(vv[j]);
    l[j] = f2bfu(vv[j] - bfu2f(h[j]));
  }
  uint2 ph = make_uint2((unsigned)h[0] | ((unsigned)h[1]<<16),
                        (unsigned)h[2] | ((unsigned)h[3]<<16));
  uint2 pl = make_uint2((unsigned)l[0] | ((unsigned)l[1]<<16),
                        (unsigned)l[2] | ((unsigned)l[3]<<16));
  *(uint2*)(hi + i) = ph;
  *(uint2*)(lo + i) = pl;
}

// ---------------- MFMA GEMM: C[M,N] = (Ahi+Alo)[M,K] * W[N,K]^T + bias ----------------
// wperm=1: weight rows gathered via dynperm (bias too); output written in permuted order.
// Chi/Clo non-null: write output as bf16 hi/lo pair (not valid with splitk).
#define GBM 128
#define GBN 64
#define GBK 32
__global__ __launch_bounds__(256) void gemm_mfma_k(
    const unsigned short* __restrict__ Ahi, const unsigned short* __restrict__ Alo,
    const void* __restrict__ Wt, long long woff,
    const void* __restrict__ bias, long long boff,
    float* __restrict__ C,
    unsigned short* __restrict__ Chi, unsigned short* __restrict__ Clo,
    int M, int Nn, int K, int relu, int kit, int splitk, int wperm,
    const int* __restrict__ flags) {
  int f32 = flags[0];
  __shared__ __align__(16) unsigned short Ah[GBM][40];
  __shared__ __align__(16) unsigned short Al[GBM][40];
  __shared__ __align__(16) unsigned short Bh[GBN][40];
  __shared__ __align__(16) unsigned short Bl[GBN][40];
  int tid = threadIdx.x;
  int lane = tid & 63, wid = tid >> 6;
  int wm = wid * 32;
  int m0 = blockIdx.x*GBM, n0 = blockIdx.y*GBN;
  int row = lane & 15, kb = (lane >> 4) * 8;
  int kbeg = 0, kend = K;
  if (splitk) { kbeg = blockIdx.z*kit*GBK; kend = kbeg + kit*GBK; if (kend > K) kend = K; }
  f32x4 zero = {0.f, 0.f, 0.f, 0.f};
  f32x4 acc[2][4];
#pragma unroll
  for (int i = 0; i < 2; ++i)
#pragma unroll
    for (int j = 0; j < 4; ++j) acc[i][j] = zero;
  int sr = tid >> 2, kq = (tid & 3) * 8;
  for (int k0 = kbeg; k0 < kend; k0 += GBK) {
#pragma unroll
    for (int p = 0; p < 2; ++p) {
      int r = sr + p*64;
      int gm = m0 + r;
      uint4 h = {0,0,0,0}, l = {0,0,0,0};
      if (gm < M) {
        size_t e = (size_t)gm*K + k0 + kq;
        h = *(const uint4*)(Ahi + e);
        l = *(const uint4*)(Alo + e);
      }
      *(uint4*)&Ah[r][kq] = h;
      *(uint4*)&Al[r][kq] = l;
    }
    {
      int gno = n0 + sr;
      int gn = wperm ? dynperm(gno) : gno;
      if (!f32) {
        uint4 h = {0,0,0,0};
        if (gno < Nn)
          h = *(const uint4*)((const unsigned short*)Wt + woff + (size_t)gn*K + k0 + kq);
        *(uint4*)&Bh[sr][kq] = h;
      } else {
        float v[8] = {0.f,0.f,0.f,0.f,0.f,0.f,0.f,0.f};
        if (gno < Nn) {
          const float* wp = (const float*)Wt + woff + (size_t)gn*K + k0 + kq;
          float4 u0 = *(const float4*)wp;
          float4 u1 = *(const float4*)(wp + 4);
          v[0]=u0.x; v[1]=u0.y; v[2]=u0.z; v[3]=u0.w;
          v[4]=u1.x; v[5]=u1.y; v[6]=u1.z; v[7]=u1.w;
        }
        unsigned short h[8], l[8];
#pragma unroll
        for (int j = 0; j < 8; ++j) {
          h[j] = f2bfu(v[j]);
          l[j] = f2bfu(v[j] - bfu2f(h[j]));
        }
        uint4 ph = {(unsigned)h[0]|((unsigned)h[1]<<16), (unsigned)h[2]|((unsigned)h[3]<<16),
                    (unsigned)h[4]|((unsigned)h[5]<<16), (unsigned)h[6]|((unsigned)h[7]<<16)};
        uint4 pl = {(unsigned)l[0]|((unsigned)l[1]<<16), (unsigned)l[2]|((unsigned)l[3]<<16),
                    (unsigned)l[4]|((unsigned)l[5]<<16), (unsigned)l[6]|((unsigned)l[7]<<16)};
        *(uint4*)&Bh[sr][kq] = ph;
        *(uint4*)&Bl[sr][kq] = pl;
      }
    }
    __syncthreads();
    short8 ah[2], al[2], bh[4];
#pragma unroll
    for (int fm = 0; fm < 2; ++fm) {
      ah[fm] = *(const short8*)&Ah[wm + fm*16 + row][kb];
      al[fm] = *(const short8*)&Al[wm + fm*16 + row][kb];
    }
#pragma unroll
    for (int fn = 0; fn < 4; ++fn) bh[fn] = *(const short8*)&Bh[fn*16 + row][kb];
#pragma unroll
    for (int fm = 0; fm < 2; ++fm)
#pragma unroll
      for (int fn = 0; fn < 4; ++fn) {
        acc[fm][fn] = __builtin_amdgcn_mfma_f32_16x16x32_bf16(ah[fm], bh[fn], acc[fm][fn], 0, 0, 0);
        acc[fm][fn] = __builtin_amdgcn_mfma_f32_16x16x32_bf16(al[fm], bh[fn], acc[fm][fn], 0, 0, 0);
      }
    if (f32) {
      short8 bl[4];
#pragma unroll
      for (int fn = 0; fn < 4; ++fn) bl[fn] = *(const short8*)&Bl[fn*16 + row][kb];
#pragma unroll
      for (int fm = 0; fm < 2; ++fm)
#pragma unroll
        for (int fn = 0; fn < 4; ++fn)
          acc[fm][fn] = __builtin_amdgcn_mfma_f32_16x16x32_bf16(ah[fm], bl[fn], acc[fm][fn], 0, 0, 0);
    }
    __syncthreads();
  }
  // epilogue: C/D layout col = lane&15, row = (lane>>4)*4 + reg
#pragma unroll
  for (int fm = 0; fm < 2; ++fm) {
    int rb = m0 + wm + fm*16 + (lane >> 4)*4;
#pragma unroll
    for (int fn = 0; fn < 4; ++fn) {
      int gc = n0 + fn*16 + row;
      if (gc >= Nn) continue;
#pragma unroll
      for (int j = 0; j < 4; ++j) {
        int gm = rb + j;
        if (gm >= M) continue;
        float v = acc[fm][fn][j];
        if (splitk) {
          atomicAdd(&C[(size_t)gm*Nn + gc], v);
        } else {
          if (bias) v += ldv(bias, boff + (wperm ? dynperm(gc) : gc), f32);
          if (relu) v = fmaxf(v, 0.f);
          if (Chi) {
            unsigned short h = f2bfu(v);
            unsigned short l = f2bfu(v - bfu2f(h));
            size_t o = (size_t)gm*Nn + gc;
            Chi[o] = h; Clo[o] = l;
          } else {
            C[(size_t)gm*Nn + gc] = v;
          }
        }
      }
    }
  }
}

// C[i] = bias[i % Nn] (or 0) — init target for split-K accumulation
__global__ __launch_bounds__(256) void init_bias_kernel(float* __restrict__ C,
                                                        const void* __restrict__ bias,
                                                        long long boff, int n, int Nn,
                                                        const int* __restrict__ flags) {
  int f32 = flags[0];
  int i = blockIdx.x*256 + threadIdx.x;
  if (i < n) C[i] = bias ? ldv(bias, boff + (i % Nn), f32) : 0.f;
}

// ---------------- fused masked MHA ----------------
__global__ __launch_bounds__(256) void attn_kernel(const float* __restrict__ qp,
                                                   const float* __restrict__ kp,
                                                   const float* __restrict__ vp,
                                                   const void* __restrict__ bboxes,
                                                   const void* __restrict__ mask,
                                                   float* __restrict__ ctx,
                                                   const int* __restrict__ flags) {
  int f32 = flags[0];
  int nq = blockIdx.x;
  int n = nq / NR, q = nq % NR;
  __shared__ float qv[DIM];
  __shared__ float sc[NHEAD*NR];
  int t = threadIdx.x;
  qv[t] = qp[(size_t)nq*DIM + t];
  __syncthreads();
  float mq = ldv(mask, nq, f32);
  float qx0 = ldv(bboxes, (long long)nq*4+0, f32);
  float qy0 = ldv(bboxes, (long long)nq*4+1, f32);
  float qx1 = ldv(bboxes, (long long)nq*4+2, f32);
  float qy1 = ldv(bboxes, (long long)nq*4+3, f32);
  float areaq = (qx1-qx0)*(qy1-qy0);
  for (int idx = t; idx < NHEAD*NR; idx += 256) {
    int h = idx / NR, k = idx % NR;
    const float* kr = kp + ((size_t)n*NR + k)*DIM + h*HD;
    const float* qh = qv + h*HD;
    float s = 0.f;
#pragma unroll
    for (int d = 0; d < HD; ++d) s += qh[d]*kr[d];
    s *= 0.17677669529663687f;   // 1/sqrt(32)
    long long bk = (long long)(n*NR + k)*4;
    float kx0 = ldv(bboxes, bk+0, f32);
    float ky0 = ldv(bboxes, bk+1, f32);
    float kx1 = ldv(bboxes, bk+2, f32);
    float ky1 = ldv(bboxes, bk+3, f32);
    float areak = (kx1-kx0)*(ky1-ky0);
    float lx = fmaxf(qx0, kx0), ly = fmaxf(qy0, ky0);
    float rx = fminf(qx1, kx1), ry = fminf(qy1, ky1);
    float iw = fmaxf(rx-lx, 0.f), ih = fmaxf(ry-ly, 0.f);
    float inter = iw*ih;
    float uni = areaq + areak - inter;
    float iou = inter / fmaxf(uni, 1e-9f);
    float mk = ldv(mask, n*NR + k, f32);
    float am = (iou < 0.5f ? 1.f : 0.f)*mq*mk + ((q == k) ? (1.f - mq) : 0.f);
    if (am > 0.f) s = -1e9f;
    sc[idx] = s;
  }
  __syncthreads();
  int wv = t >> 6, lane = t & 63;
  for (int h = wv*2; h < wv*2 + 2; ++h) {
    float mx = -3.4e38f;
    for (int k = lane; k < NR; k += 64) mx = fmaxf(mx, sc[h*NR + k]);
    mx = wmaxf(mx);
    float sum = 0.f;
    for (int k = lane; k < NR; k += 64) {
      float e = expf(sc[h*NR + k] - mx);
      sc[h*NR + k] = e;
      sum += e;
    }
    sum = wsum(sum);
    float inv = 1.f / sum;
    for (int k = lane; k < NR; k += 64) sc[h*NR + k] *= inv;
  }
  __syncthreads();
  int h = t >> 5, d = t & 31;
  float acc = 0.f;
  const float* vb = vp + (size_t)n*NR*DIM + h*HD + d;
  for (int k = 0; k < NR; ++k) acc += sc[h*NR + k] * vb[(size_t)k*DIM];
  ctx[(size_t)nq*DIM + t] = acc;
}

// ---------------- norm1 ----------------
__global__ __launch_bounds__(256) void norm1_kernel(const float* __restrict__ pf0,
                                                    const float* __restrict__ tgt2,
                                                    const void* __restrict__ mask,
                                                    float* __restrict__ pf1,
                                                    const int* __restrict__ flags) {
  int f32 = flags[0];
  int r = blockIdx.x, t = threadIdx.x;
  __shared__ float s4[4];
  float x = pf0[(size_t)r*DIM + t] + tgt2[(size_t)r*DIM + t];
  float mean = bsum(x, s4) * (1.f/DIM);
  float df = x - mean;
  float var = bsum(df*df, s4) * (1.f/DIM);
  float y = df * rsqrtf(var + 1e-5f);
  pf1[(size_t)r*DIM + t] = y * ldv(mask, r, f32);
}

// ---------------- fused MFMA DynamicConv ----------------
// One block (4 waves) per instance. Phi/Plo hold permuted params:
//   [0,16384): p1T[e][d] (d contiguous); [16384,32768): p2T[d][e] (e contiguous).
// dyn1: A = roi (direct global frags, exact bf16), B = p1T hi/lo.
// LN+relu in-register (16-lane shfl), f1 -> LDS hi/lo.
// dyn2: A = f1 (LDS), B = p2T hi/lo. LN+relu in-register, f2 -> global hi/lo.
__global__ __launch_bounds__(256) void dyn_mfma_kernel(
    const void* __restrict__ roi,
    const unsigned short* __restrict__ Phi, const unsigned short* __restrict__ Plo,
    unsigned short* __restrict__ f2hi, unsigned short* __restrict__ f2lo,
    int r0, const int* __restrict__ flags) {
  int f32 = flags[0];
  int ci = blockIdx.x;
  int rr = r0 + ci;
  __shared__ __align__(16) unsigned short F1h[64][72];
  __shared__ __align__(16) unsigned short F1l[64][72];
  int tid = threadIdx.x;
  int lane = tid & 63, wid = tid >> 6;
  int rlo = lane & 15, rhi = lane >> 4;
  size_t pcb = (size_t)ci * (2*DIM*DDIM);
  f32x4 zero = {0.f,0.f,0.f,0.f};
  // ---- dyn1: M=64(pad) N=64 K=256; wave w owns m-frag w (rows 16w..16w+15)
  f32x4 acc1[4];
#pragma unroll
  for (int i = 0; i < 4; ++i) acc1[i] = zero;
  int s_a = 16*wid + rlo;
  int s_c = s_a > SS-1 ? SS-1 : s_a;       // clamp pad rows (finite garbage)
  for (int ks = 0; ks < 8; ++ks) {
    int k = ks*32 + rhi*8;
    short8 ah, al = (short8)0;
    if (!f32) {
      ah = *(const short8*)((const unsigned short*)roi + ((size_t)s_c*MTOT + rr)*DIM + k);
    } else {
      const float* rp = (const float*)roi + ((size_t)s_c*MTOT + rr)*DIM + k;
      float4 u0 = *(const float4*)rp, u1 = *(const float4*)(rp + 4);
      float v[8] = {u0.x,u0.y,u0.z,u0.w,u1.x,u1.y,u1.z,u1.w};
#pragma unroll
      for (int j = 0; j < 8; ++j) {
        unsigned short h = f2bfu(v[j]);
        ah[j] = (short)h;
        al[j] = (short)f2bfu(v[j] - bfu2f(h));
      }
    }
#pragma unroll
    for (int fn = 0; fn < 4; ++fn) {
      int e = fn*16 + rlo;
      short8 bh = *(const short8*)(Phi + pcb + (size_t)e*DIM + k);
      short8 bl = *(const short8*)(Plo + pcb + (size_t)e*DIM + k);
      acc1[fn] = __builtin_amdgcn_mfma_f32_16x16x32_bf16(ah, bh, acc1[fn], 0, 0, 0);
      acc1[fn] = __builtin_amdgcn_mfma_f32_16x16x32_bf16(ah, bl, acc1[fn], 0, 0, 0);
      if (f32) acc1[fn] = __builtin_amdgcn_mfma_f32_16x16x32_bf16(al, bh, acc1[fn], 0, 0, 0);
    }
  }
  // ---- LN1 over e (64) + relu + split -> LDS
#pragma unroll
  for (int j = 0; j < 4; ++j) {
    float x[4], sum = 0.f;
#pragma unroll
    for (int fn = 0; fn < 4; ++fn) { x[fn] = acc1[fn][j]; sum += x[fn]; }
#pragma unroll
    for (int o = 8; o > 0; o >>= 1) sum += __shfl_xor(sum, o, 64);
    float mean = sum * (1.f/DDIM);
    float vs = 0.f;
#pragma unroll
    for (int fn = 0; fn < 4; ++fn) { float d0 = x[fn]-mean; vs += d0*d0; }
#pragma unroll
    for (int o = 8; o > 0; o >>= 1) vs += __shfl_xor(vs, o, 64);
    float rs = rsqrtf(vs*(1.f/DDIM) + 1e-5f);
    int row = 16*wid + rhi*4 + j;
#pragma unroll
    for (int fn = 0; fn < 4; ++fn) {
      float y = fmaxf((x[fn]-mean)*rs, 0.f);
      unsigned short h = f2bfu(y);
      F1h[row][fn*16 + rlo] = h;
      F1l[row][fn*16 + rlo] = f2bfu(y - bfu2f(h));
    }
  }
  __syncthreads();
  // ---- dyn2: M=64 N=256 K=64; wave w owns m-frag w, all 16 n-frags
  f32x4 acc2[16];
#pragma unroll
  for (int i = 0; i < 16; ++i) acc2[i] = zero;
  for (int ks = 0; ks < 2; ++ks) {
    int k = ks*32 + rhi*8;
    short8 ah = *(const short8*)&F1h[16*wid + rlo][k];
    short8 al = *(const short8*)&F1l[16*wid + rlo][k];
#pragma unroll
    for (int fn = 0; fn < 16; ++fn) {
      int d0 = fn*16 + rlo;
      short8 bh = *(const short8*)(Phi + pcb + DIM*DDIM + (size_t)d0*DDIM + k);
      short8 bl = *(const short8*)(Plo + pcb + DIM*DDIM + (size_t)d0*DDIM + k);
      acc2[fn] = __builtin_amdgcn_mfma_f32_16x16x32_bf16(ah, bh, acc2[fn], 0, 0, 0);
      acc2[fn] = __builtin_amdgcn_mfma_f32_16x16x32_bf16(al, bh, acc2[fn], 0, 0, 0);
      acc2[fn] = __builtin_amdgcn_mfma_f32_16x16x32_bf16(ah, bl, acc2[fn], 0, 0, 0);
    }
  }
  // ---- LN2 over d (256) + relu + split -> global f2
#pragma unroll
  for (int j = 0; j < 4; ++j) {
    float sum = 0.f;
#pragma unroll
    for (int fn = 0; fn < 16; ++fn) sum += acc2[fn][j];
#pragma unroll
    for (int o = 8; o > 0; o >>= 1) sum += __shfl_xor(sum, o, 64);
    float mean = sum * (1.f/DIM);
    float vs = 0.f;
#pragma unroll
    for (int fn = 0; fn < 16; ++fn) { float d0 = acc2[fn][j]-mean; vs += d0*d0; }
#pragma unroll
    for (int o = 8; o > 0; o >>= 1) vs += __shfl_xor(vs, o, 64);
    float rs = rsqrtf(vs*(1.f/DIM) + 1e-5f);
    int s = 16*wid + rhi*4 + j;
    if (s < SS) {
      size_t ob = ((size_t)ci*SS + s)*DIM;
#pragma unroll
      for (int fn = 0; fn < 16; ++fn) {
        float y = fmaxf((acc2[fn][j]-mean)*rs, 0.f);
        unsigned short h = f2bfu(y);
        f2hi[ob + fn*16 + rlo] = h;
        f2lo[ob + fn*16 + rlo] = f2bfu(y - bfu2f(h));
      }
    }
  }
}

// ---------------- normdyn ----------------
__global__ __launch_bounds__(256) void normdyn_kernel(const float* __restrict__ g,
                                                      const float* __restrict__ pf1,
                                                      float* __restrict__ pfB) {
  int r = blockIdx.x, t = threadIdx.x;
  __shared__ float s4[4];
  float x = g[(size_t)r*DIM + t];
  float mean = bsum(x, s4)*(1.f/DIM);
  float df = x - mean;
  float var = bsum(df*df, s4)*(1.f/DIM);
  float y = fmaxf(df*rsqrtf(var+1e-5f), 0.f);
  float x2 = pf1[(size_t)r*DIM + t] + y;
  float mean2 = bsum(x2, s4)*(1.f/DIM);
  float df2 = x2 - mean2;
  float var2 = bsum(df2*df2, s4)*(1.f/DIM);
  pfB[(size_t)r*DIM + t] = df2*rsqrtf(var2+1e-5f);
}

// ---------------- norm3 ----------------
__global__ __launch_bounds__(256) void norm3_kernel(const float* __restrict__ pfB,
                                                    const float* __restrict__ t2,
                                                    const void* __restrict__ mask,
                                                    float* __restrict__ fc,
                                                    const int* __restrict__ flags) {
  int f32 = flags[0];
  int r = blockIdx.x, t = threadIdx.x;
  __shared__ float s4[4];
  float x = pfB[(size_t)r*DIM + t] + t2[(size_t)r*DIM + t];
  float mean = bsum(x, s4)*(1.f/DIM);
  float df = x - mean;
  float var = bsum(df*df, s4)*(1.f/DIM);
  float y = df*rsqrtf(var+1e-5f);
  fc[(size_t)r*DIM + t] = y * ldv(mask, r, f32);
}

// ---------------- lncls ----------------
__global__ __launch_bounds__(256) void lncls_kernel(const float* __restrict__ g,
                                                    float* __restrict__ out) {
  int r = blockIdx.x, t = threadIdx.x;
  __shared__ float s4[4];
  float x = g[(size_t)r*DIM + t];
  float mean = bsum(x, s4)*(1.f/DIM);
  float df = x - mean;
  float var = bsum(df*df, s4)*(1.f/DIM);
  out[(size_t)r*DIM + t] = fmaxf(df*rsqrtf(var+1e-5f), 0.f);
}

// ---------------- final ----------------
__global__ __launch_bounds__(256) void final_kernel(const float* __restrict__ logf,
                                                    const int* __restrict__ flags,
                                                    void* __restrict__ out, int n) {
  int f32 = flags[0];
  int i = blockIdx.x*256 + threadIdx.x;
  if (i < n) {
    float v = logf[i];
    if (!(fabsf(v) <= 3.0e38f)) v = 0.f;
    if (i == 0) {
      int code = 0;
      for (int s = NFLAGS - 1; s >= 1; --s) if (flags[s]) code = 100 + 4*s;
      if (code) v = (float)code;
    }
    if (f32) ((float*)out)[i] = v;
    else ((bf16*)out)[i] = __float2bfloat16(v);
  }
}

extern "C" void kernel_launch(void* const* d_in, const int* in_sizes, int n_in,
                              void* d_out, int out_size, void* d_ws, size_t ws_size,
                              hipStream_t stream) {
  const void* bboxes     = d_in[0];
  const void* pro        = d_in[1];
  const void* roi        = d_in[2];
  const void* query      = d_in[3];
  const void* mask       = d_in[4];
  const void* w_qkv      = d_in[5];
  const void* b_qkv      = d_in[6];
  const void* w_attn_out = d_in[7];
  const void* b_attn_out = d_in[8];
  const void* w_dyn      = d_in[9];
  const void* b_dyn      = d_in[10];
  const void* w_dyn_out  = d_in[11];
  const void* b_dyn_out  = d_in[12];
  const void* w_ff1      = d_in[13];
  const void* b_ff1      = d_in[14];
  const void* w_ff2      = d_in[15];
  const void* b_ff2      = d_in[16];
  const void* w_cls      = d_in[17];
  const void* w_logits   = d_in[18];
  const void* b_logits   = d_in[19];
  (void)in_sizes; (void)n_in; (void)out_size;

  const size_t RD = (size_t)MTOT*DIM;

  // ---- workspace tiers ----
  const size_t DYNROW = (size_t)2*DIM*DDIM;   // Pc: hi/lo shorts == 1 float per param
  size_t wsf = ws_size / sizeof(float);
  size_t fixedf = 5*RD + (size_t)MTOT*NCLS + 256;
  auto spl_of = [&](size_t chn, size_t fh) {
    size_t a = chn*(size_t)SS*DIM, b = fh*(size_t)FFD;
    size_t m = a > b ? a : b; return m > RD ? m : RD;
  };
  auto need = [&](size_t chn, size_t fh) {
    return fixedf + chn*DYNROW + fh*FFD + spl_of(chn, fh);
  };
  int CHN = 64, FH = 300;
  if (wsf >= need(2400, MTOT))      { CHN = 2400; FH = MTOT; }
  else if (wsf >= need(1200, MTOT)) { CHN = 1200; FH = MTOT; }
  else if (wsf >= need(600, MTOT))  { CHN = 600;  FH = MTOT; }
  else if (wsf >= need(300, MTOT))  { CHN = 300;  FH = MTOT; }
  else if (wsf >= need(150, 300))   { CHN = 150;  FH = 300;  }
  const size_t SPL = spl_of(CHN, FH);

  float* Wsp = (float*)d_ws;
  size_t off = 0;
  auto alloc = [&](size_t n) { float* p = Wsp + off; off += n; return p; };
  float* A = alloc(RD);
  float* B = alloc(RD);
  float* C = alloc(RD);
  float* D = alloc(RD);
  float* E = alloc(RD);
  float* logf = alloc((size_t)MTOT*NCLS);
  float* ffh = alloc((size_t)FH*FFD);          // bf16 hi/lo pair for ffn hidden
  float* Pc  = alloc((size_t)CHN*2*DIM*DDIM);  // bf16 hi/lo pair, permuted layout
  unsigned short* Ahi = (unsigned short*)alloc(SPL/2 + 8);
  unsigned short* Alo = (unsigned short*)alloc(SPL/2 + 8);
  int* flags = (int*)(Wsp + off);
  unsigned short* ffhi = (unsigned short*)ffh;
  unsigned short* fflo = ffhi + (size_t)FH*FFD;
  unsigned short* Pchi = (unsigned short*)Pc;
  unsigned short* Pclo = Pchi + (size_t)CHN*2*DIM*DDIM;

  dim3 b256(256);
  auto split = [&](const float* x, long long n) {
    long long n4 = n/4;
    split_kernel<<<(int)((n4 + 255)/256), b256, 0, stream>>>(x, Ahi, Alo, n4);
  };
  auto gemm_full = [&](const unsigned short* Ah_, const unsigned short* Al_,
                       const void* Wm, long long woff,
                       const void* bias, long long boff, float* Cm,
                       unsigned short* Chi, unsigned short* Clo,
                       int M, int Nn, int K, int relu, int wperm) {
    int gm = (M + GBM - 1)/GBM;
    int gn = (Nn + GBN - 1)/GBN;
    int ntiles = K / GBK;
    int ks = 1;
    if (!relu && !Chi && gm*gn < 512) {
      ks = (768 + gm*gn - 1)/(gm*gn);
      if (ks > ntiles) ks = ntiles;
    }
    int kit = (ntiles + ks - 1)/ks;
    ks = (ntiles + kit - 1)/kit;
    if (ks > 1) {
      int n = M*Nn;
      init_bias_kernel<<<(n + 255)/256, b256, 0, stream>>>(Cm, bias, boff, n, Nn, flags);
      gemm_mfma_k<<<dim3(gm, gn, ks), b256, 0, stream>>>(Ah_, Al_, Wm, woff, nullptr, 0,
                                                         Cm, nullptr, nullptr,
                                                         M, Nn, K, relu, kit, 1, 0, flags);
    } else {
      gemm_mfma_k<<<dim3(gm, gn, 1), b256, 0, stream>>>(Ah_, Al_, Wm, woff, bias, boff,
                                                        Cm, Chi, Clo,
                                                        M, Nn, K, relu, kit, 0, wperm, flags);
    }
  };
  auto gemm = [&](const unsigned short* Ah_, const unsigned short* Al_,
                  const void* Wm, long long woff,
                  const void* bias, long long boff, float* Cm,
                  int M, int Nn, int K, int relu) {
    gemm_full(Ah_, Al_, Wm, woff, bias, boff, Cm, nullptr, nullptr, M, Nn, K, relu, 0);
  };

  zero_flags_kernel<<<1, 64, 0, stream>>>(flags);
  detect_dtype_kernel<<<256, b256, 0, stream>>>(w_qkv, 3LL*DIM*DIM, flags);

  prep_kernel<<<MTOT, b256, 0, stream>>>(pro, query, A, B, flags);  // A=pf0 B=qk
  split(B, RD);
  gemm(Ahi, Alo, w_qkv, 0,                  b_qkv, 0,     C, MTOT, DIM, DIM, 0);  // C=qp
  gemm(Ahi, Alo, w_qkv, (long long)DIM*DIM, b_qkv, DIM,   D, MTOT, DIM, DIM, 0);  // D=kp
  split(A, RD);
  gemm(Ahi, Alo, w_qkv, 2LL*DIM*DIM,        b_qkv, 2*DIM, E, MTOT, DIM, DIM, 0);  // E=vp
  attn_kernel<<<MTOT, b256, 0, stream>>>(C, D, E, bboxes, mask, B, flags);        // B=ctx
  split(B, RD);
  gemm(Ahi, Alo, w_attn_out, 0, b_attn_out, 0, C, MTOT, DIM, DIM, 0);             // C=tgt2
  norm1_kernel<<<MTOT, b256, 0, stream>>>(A, C, mask, D, flags);                  // D=pf1

  for (int r0 = 0; r0 < MTOT; r0 += CHN) {
    int m = MTOT - r0 < CHN ? MTOT - r0 : CHN;
    split(D + (size_t)r0*DIM, (long long)m*DIM);
    // P-GEMM: permuted weight gather -> Pc written as p1T/p2T bf16 hi/lo, coalesced
    gemm_full(Ahi, Alo, w_dyn, 0, b_dyn, 0, nullptr, Pchi, Pclo,
              m, 2*DIM*DDIM, DIM, 0, 1);
    // fused MFMA dyn1+LN+relu+dyn2+LN+relu; writes f2 hi/lo into Ahi/Alo
    dyn_mfma_kernel<<<m, b256, 0, stream>>>(roi, Pchi, Pclo, Ahi, Alo, r0, flags);
    gemm(Ahi, Alo, w_dyn_out, 0, b_dyn_out, 0, E + (size_t)r0*DIM,
         m, DIM, SS*DIM, 0);                                                      // E=gdyn
  }
  normdyn_kernel<<<MTOT, b256, 0, stream>>>(E, D, A);                             // A=pfB

  for (int r0 = 0; r0 < MTOT; r0 += FH) {
    int m = MTOT - r0 < FH ? MTOT - r0 : FH;
    split(A + (size_t)r0*DIM, (long long)m*DIM);
    gemm_full(Ahi, Alo, w_ff1, 0, b_ff1, 0, nullptr, ffhi, fflo, m, FFD, DIM, 1, 0);
    gemm(ffhi, fflo, w_ff2, 0, b_ff2, 0, B + (size_t)r0*DIM, m, DIM, FFD, 0);     // B=t2
  }
  norm3_kernel<<<MTOT, b256, 0, stream>>>(A, B, mask, C, flags);                  // C=fcb

  split(C, RD);
  gemm(Ahi, Alo, w_cls, 0, nullptr, 0, D, MTOT, DIM, DIM, 0);                     // D=clsg
  lncls_kernel<<<MTOT, b256, 0, stream>>>(D, E);                                  // E=clsf
  split(E, RD);
  gemm(Ahi, Alo, w_logits, 0, b_logits, 0, logf, MTOT, NCLS, DIM, 0);

  final_kernel<<<((MTOT*NCLS)+255)/256, b256, 0, stream>>>(logf, flags, d_out, MTOT*NCLS);
}

// Round 6
// 1348.249 us; speedup vs baseline: 1.5492x; 1.0123x over previous
//
#include <hip/hip_runtime.h>
#include <hip/hip_bf16.h>

using bf16 = __hip_bfloat16;

#define NIMG 8
#define NR 300
#define DIM 256
#define NHEAD 8
#define HD 32
#define SS 49
#define DDIM 64
#define FFD 2048
#define NCLS 80
#define MTOT (NIMG*NR)      // 2400
#define NFLAGS 32

typedef short short8 __attribute__((ext_vector_type(8)));
typedef float f32x4 __attribute__((ext_vector_type(4)));

// dual-dtype load: f32==1 -> buffer is float32, else bf16 (element index i)
__device__ inline float ldv(const void* p, long long i, int f32) {
  return f32 ? ((const float*)p)[i] : __bfloat162float(((const bf16*)p)[i]);
}

__device__ inline unsigned short f2bfu(float x) {
  bf16 b = __float2bfloat16(x);
  unsigned short u; __builtin_memcpy(&u, &b, 2); return u;
}
__device__ inline float bfu2f(unsigned short u) {
  bf16 b; __builtin_memcpy(&b, &u, 2); return __bfloat162float(b);
}
// packed hi/lo word: bits[15:0]=bf16(hi), bits[31:16]=bf16(x-hi)
__device__ inline unsigned packhl(float x) {
  unsigned short h = f2bfu(x);
  unsigned short l = f2bfu(x - bfu2f(h));
  return (unsigned)h | ((unsigned)l << 16);
}
// unpack 8 packed words (32B) -> hi uint4 + lo uint4 (each 8 bf16)
__device__ inline void unpack8(const unsigned* __restrict__ p, uint4& h, uint4& l) {
  uint4 a0 = *(const uint4*)p;
  uint4 a1 = *(const uint4*)(p + 4);
  h.x = (a0.x & 0xffffu) | (a0.y << 16);
  h.y = (a0.z & 0xffffu) | (a0.w << 16);
  h.z = (a1.x & 0xffffu) | (a1.y << 16);
  h.w = (a1.z & 0xffffu) | (a1.w << 16);
  l.x = (a0.x >> 16) | (a0.y & 0xffff0000u);
  l.y = (a0.z >> 16) | (a0.w & 0xffff0000u);
  l.z = (a1.x >> 16) | (a1.y & 0xffff0000u);
  l.w = (a1.z >> 16) | (a1.w & 0xffff0000u);
}
__device__ inline void unpack8s(const unsigned* __restrict__ p, short8& h, short8& l) {
  uint4 H, L; unpack8(p, H, L);
  __builtin_memcpy(&h, &H, 16);
  __builtin_memcpy(&l, &L, 16);
}

// weight-row permutation for the dyn P-GEMM
__device__ inline int dynperm(int n) {
  if (n < DIM*DDIM) { int e = n >> 8, d = n & 255; return d*DDIM + e; }
  int q = n - DIM*DDIM; int d = q >> 6, e = q & 63; return DIM*DDIM + e*DIM + d;
}

__device__ inline float wsum(float v) {
#pragma unroll
  for (int o = 32; o > 0; o >>= 1) v += __shfl_xor(v, o, 64);
  return v;
}
__device__ inline float wmaxf(float v) {
#pragma unroll
  for (int o = 32; o > 0; o >>= 1) v = fmaxf(v, __shfl_xor(v, o, 64));
  return v;
}
__device__ inline float bsum(float v, float* s4) {
  v = wsum(v);
  int w = threadIdx.x >> 6;
  if ((threadIdx.x & 63) == 0) s4[w] = v;
  __syncthreads();
  float r = s4[0] + s4[1] + s4[2] + s4[3];
  __syncthreads();
  return r;
}

// ---------------- diagnostics ----------------
__global__ __launch_bounds__(64) void zero_flags_kernel(int* flags) {
  if (threadIdx.x < NFLAGS) flags[threadIdx.x] = 0;
}
__global__ __launch_bounds__(256) void detect_dtype_kernel(const void* __restrict__ p,
                                                           long long n,
                                                           int* __restrict__ flags) {
  long long i = (long long)blockIdx.x*256 + threadIdx.x;
  long long stride = (long long)gridDim.x*256;
  int f32 = 0;
  for (; i < n; i += stride) {
    float v = __bfloat162float(((const bf16*)p)[i]);
    if (!(fabsf(v) <= 1.0e20f)) { f32 = 1; break; }
  }
  if (f32) atomicOr(&flags[0], 1);
}

// ---------------- prep ----------------
__global__ __launch_bounds__(256) void prep_kernel(const void* __restrict__ pro,
                                                   const void* __restrict__ query,
                                                   float* __restrict__ pf0,
                                                   float* __restrict__ qk,
                                                   const int* __restrict__ flags) {
  int f32 = flags[0];
  int i = blockIdx.x*256 + threadIdx.x;
  float p = ldv(pro, i, f32);
  pf0[i] = p;
  qk[i] = p + ldv(query, i, f32);
}

// ---------------- split fp32 -> packed hi/lo u32 ----------------
__global__ __launch_bounds__(256) void split_kernel(const float* __restrict__ x,
                                                    unsigned* __restrict__ pk,
                                                    long long n4) {
  long long q = (long long)blockIdx.x*256 + threadIdx.x;
  if (q >= n4) return;
  long long i = q*4;
  float4 v = *(const float4*)(x + i);
  uint4 o;
  o.x = packhl(v.x); o.y = packhl(v.y); o.z = packhl(v.z); o.w = packhl(v.w);
  *(uint4*)(pk + i) = o;
}

// ---------------- MFMA GEMM: C[M,N] = A[M,K] * W[N,K]^T + bias ----------------
// A is packed hi/lo u32 per element. Weights: bf16 -> exact (2 MFMA terms);
// fp32 -> split in staging, 3rd term a_hi*w_lo added.
// wperm=1: weight rows gathered via dynperm (bias too).
// Cpk non-null: write output as packed hi/lo u32 (not valid with splitk).
#define GBM 128
#define GBN 64
#define GBK 32
__global__ __launch_bounds__(256) void gemm_mfma_k(
    const unsigned* __restrict__ Apk,
    const void* __restrict__ Wt, long long woff,
    const void* __restrict__ bias, long long boff,
    float* __restrict__ C, unsigned* __restrict__ Cpk,
    int M, int Nn, int K, int relu, int kit, int splitk, int wperm,
    const int* __restrict__ flags) {
  int f32 = flags[0];
  __shared__ __align__(16) unsigned short Ah[GBM][40];
  __shared__ __align__(16) unsigned short Al[GBM][40];
  __shared__ __align__(16) unsigned short Bh[GBN][40];
  __shared__ __align__(16) unsigned short Bl[GBN][40];
  int tid = threadIdx.x;
  int lane = tid & 63, wid = tid >> 6;
  int wm = wid * 32;
  int m0 = blockIdx.x*GBM, n0 = blockIdx.y*GBN;
  int row = lane & 15, kb = (lane >> 4) * 8;
  int kbeg = 0, kend = K;
  if (splitk) { kbeg = blockIdx.z*kit*GBK; kend = kbeg + kit*GBK; if (kend > K) kend = K; }
  f32x4 zero = {0.f, 0.f, 0.f, 0.f};
  f32x4 acc[2][4];
#pragma unroll
  for (int i = 0; i < 2; ++i)
#pragma unroll
    for (int j = 0; j < 4; ++j) acc[i][j] = zero;
  int sr = tid >> 2, kq = (tid & 3) * 8;
  for (int k0 = kbeg; k0 < kend; k0 += GBK) {
#pragma unroll
    for (int p = 0; p < 2; ++p) {
      int r = sr + p*64;
      int gm = m0 + r;
      uint4 h = {0,0,0,0}, l = {0,0,0,0};
      if (gm < M) unpack8(Apk + (size_t)gm*K + k0 + kq, h, l);
      *(uint4*)&Ah[r][kq] = h;
      *(uint4*)&Al[r][kq] = l;
    }
    {
      int gno = n0 + sr;
      int gn = wperm ? dynperm(gno) : gno;
      if (!f32) {
        uint4 h = {0,0,0,0};
        if (gno < Nn)
          h = *(const uint4*)((const unsigned short*)Wt + woff + (size_t)gn*K + k0 + kq);
        *(uint4*)&Bh[sr][kq] = h;
      } else {
        float v[8] = {0.f,0.f,0.f,0.f,0.f,0.f,0.f,0.f};
        if (gno < Nn) {
          const float* wp = (const float*)Wt + woff + (size_t)gn*K + k0 + kq;
          float4 u0 = *(const float4*)wp;
          float4 u1 = *(const float4*)(wp + 4);
          v[0]=u0.x; v[1]=u0.y; v[2]=u0.z; v[3]=u0.w;
          v[4]=u1.x; v[5]=u1.y; v[6]=u1.z; v[7]=u1.w;
        }
        unsigned short h[8], l[8];
#pragma unroll
        for (int j = 0; j < 8; ++j) {
          h[j] = f2bfu(v[j]);
          l[j] = f2bfu(v[j] - bfu2f(h[j]));
        }
        uint4 ph = {(unsigned)h[0]|((unsigned)h[1]<<16), (unsigned)h[2]|((unsigned)h[3]<<16),
                    (unsigned)h[4]|((unsigned)h[5]<<16), (unsigned)h[6]|((unsigned)h[7]<<16)};
        uint4 pl = {(unsigned)l[0]|((unsigned)l[1]<<16), (unsigned)l[2]|((unsigned)l[3]<<16),
                    (unsigned)l[4]|((unsigned)l[5]<<16), (unsigned)l[6]|((unsigned)l[7]<<16)};
        *(uint4*)&Bh[sr][kq] = ph;
        *(uint4*)&Bl[sr][kq] = pl;
      }
    }
    __syncthreads();
    short8 ah[2], al[2], bh[4];
#pragma unroll
    for (int fm = 0; fm < 2; ++fm) {
      ah[fm] = *(const short8*)&Ah[wm + fm*16 + row][kb];
      al[fm] = *(const short8*)&Al[wm + fm*16 + row][kb];
    }
#pragma unroll
    for (int fn = 0; fn < 4; ++fn) bh[fn] = *(const short8*)&Bh[fn*16 + row][kb];
#pragma unroll
    for (int fm = 0; fm < 2; ++fm)
#pragma unroll
      for (int fn = 0; fn < 4; ++fn) {
        acc[fm][fn] = __builtin_amdgcn_mfma_f32_16x16x32_bf16(ah[fm], bh[fn], acc[fm][fn], 0, 0, 0);
        acc[fm][fn] = __builtin_amdgcn_mfma_f32_16x16x32_bf16(al[fm], bh[fn], acc[fm][fn], 0, 0, 0);
      }
    if (f32) {
      short8 bl[4];
#pragma unroll
      for (int fn = 0; fn < 4; ++fn) bl[fn] = *(const short8*)&Bl[fn*16 + row][kb];
#pragma unroll
      for (int fm = 0; fm < 2; ++fm)
#pragma unroll
        for (int fn = 0; fn < 4; ++fn)
          acc[fm][fn] = __builtin_amdgcn_mfma_f32_16x16x32_bf16(ah[fm], bl[fn], acc[fm][fn], 0, 0, 0);
    }
    __syncthreads();
  }
  // epilogue: C/D layout col = lane&15, row = (lane>>4)*4 + reg
#pragma unroll
  for (int fm = 0; fm < 2; ++fm) {
    int rb = m0 + wm + fm*16 + (lane >> 4)*4;
#pragma unroll
    for (int fn = 0; fn < 4; ++fn) {
      int gc = n0 + fn*16 + row;
      if (gc >= Nn) continue;
#pragma unroll
      for (int j = 0; j < 4; ++j) {
        int gm = rb + j;
        if (gm >= M) continue;
        float v = acc[fm][fn][j];
        if (splitk) {
          atomicAdd(&C[(size_t)gm*Nn + gc], v);
        } else {
          if (bias) v += ldv(bias, boff + (wperm ? dynperm(gc) : gc), f32);
          if (relu) v = fmaxf(v, 0.f);
          if (Cpk) Cpk[(size_t)gm*Nn + gc] = packhl(v);
          else C[(size_t)gm*Nn + gc] = v;
        }
      }
    }
  }
}

// C[i] = bias[i % Nn] (or 0) — init target for split-K accumulation
__global__ __launch_bounds__(256) void init_bias_kernel(float* __restrict__ C,
                                                        const void* __restrict__ bias,
                                                        long long boff, int n, int Nn,
                                                        const int* __restrict__ flags) {
  int f32 = flags[0];
  int i = blockIdx.x*256 + threadIdx.x;
  if (i < n) C[i] = bias ? ldv(bias, boff + (i % Nn), f32) : 0.f;
}

// ---------------- fused masked MHA ----------------
__global__ __launch_bounds__(256) void attn_kernel(const float* __restrict__ qp,
                                                   const float* __restrict__ kp,
                                                   const float* __restrict__ vp,
                                                   const void* __restrict__ bboxes,
                                                   const void* __restrict__ mask,
                                                   float* __restrict__ ctx,
                                                   const int* __restrict__ flags) {
  int f32 = flags[0];
  int nq = blockIdx.x;
  int n = nq / NR, q = nq % NR;
  __shared__ float qv[DIM];
  __shared__ float sc[NHEAD*NR];
  int t = threadIdx.x;
  qv[t] = qp[(size_t)nq*DIM + t];
  __syncthreads();
  float mq = ldv(mask, nq, f32);
  float qx0 = ldv(bboxes, (long long)nq*4+0, f32);
  float qy0 = ldv(bboxes, (long long)nq*4+1, f32);
  float qx1 = ldv(bboxes, (long long)nq*4+2, f32);
  float qy1 = ldv(bboxes, (long long)nq*4+3, f32);
  float areaq = (qx1-qx0)*(qy1-qy0);
  for (int idx = t; idx < NHEAD*NR; idx += 256) {
    int h = idx / NR, k = idx % NR;
    const float* kr = kp + ((size_t)n*NR + k)*DIM + h*HD;
    const float* qh = qv + h*HD;
    float s = 0.f;
#pragma unroll
    for (int d = 0; d < HD; ++d) s += qh[d]*kr[d];
    s *= 0.17677669529663687f;   // 1/sqrt(32)
    long long bk = (long long)(n*NR + k)*4;
    float kx0 = ldv(bboxes, bk+0, f32);
    float ky0 = ldv(bboxes, bk+1, f32);
    float kx1 = ldv(bboxes, bk+2, f32);
    float ky1 = ldv(bboxes, bk+3, f32);
    float areak = (kx1-kx0)*(ky1-ky0);
    float lx = fmaxf(qx0, kx0), ly = fmaxf(qy0, ky0);
    float rx = fminf(qx1, kx1), ry = fminf(qy1, ky1);
    float iw = fmaxf(rx-lx, 0.f), ih = fmaxf(ry-ly, 0.f);
    float inter = iw*ih;
    float uni = areaq + areak - inter;
    float iou = inter / fmaxf(uni, 1e-9f);
    float mk = ldv(mask, n*NR + k, f32);
    float am = (iou < 0.5f ? 1.f : 0.f)*mq*mk + ((q == k) ? (1.f - mq) : 0.f);
    if (am > 0.f) s = -1e9f;
    sc[idx] = s;
  }
  __syncthreads();
  int wv = t >> 6, lane = t & 63;
  for (int h = wv*2; h < wv*2 + 2; ++h) {
    float mx = -3.4e38f;
    for (int k = lane; k < NR; k += 64) mx = fmaxf(mx, sc[h*NR + k]);
    mx = wmaxf(mx);
    float sum = 0.f;
    for (int k = lane; k < NR; k += 64) {
      float e = expf(sc[h*NR + k] - mx);
      sc[h*NR + k] = e;
      sum += e;
    }
    sum = wsum(sum);
    float inv = 1.f / sum;
    for (int k = lane; k < NR; k += 64) sc[h*NR + k] *= inv;
  }
  __syncthreads();
  int h = t >> 5, d = t & 31;
  float acc = 0.f;
  const float* vb = vp + (size_t)n*NR*DIM + h*HD + d;
  for (int k = 0; k < NR; ++k) acc += sc[h*NR + k] * vb[(size_t)k*DIM];
  ctx[(size_t)nq*DIM + t] = acc;
}

// ---------------- norm1 ----------------
__global__ __launch_bounds__(256) void norm1_kernel(const float* __restrict__ pf0,
                                                    const float* __restrict__ tgt2,
                                                    const void* __restrict__ mask,
                                                    float* __restrict__ pf1,
                                                    const int* __restrict__ flags) {
  int f32 = flags[0];
  int r = blockIdx.x, t = threadIdx.x;
  __shared__ float s4[4];
  float x = pf0[(size_t)r*DIM + t] + tgt2[(size_t)r*DIM + t];
  float mean = bsum(x, s4) * (1.f/DIM);
  float df = x - mean;
  float var = bsum(df*df, s4) * (1.f/DIM);
  float y = df * rsqrtf(var + 1e-5f);
  pf1[(size_t)r*DIM + t] = y * ldv(mask, r, f32);
}

// ---------------- fused MFMA DynamicConv ----------------
// One block (4 waves) per instance. Ppk packed hi/lo params, permuted layout:
//   [0,16384): p1T[e][d] (d contiguous); [16384,32768): p2T[d][e] (e contiguous).
__global__ __launch_bounds__(256) void dyn_mfma_kernel(
    const void* __restrict__ roi,
    const unsigned* __restrict__ Ppk,
    unsigned* __restrict__ f2pk,
    int r0, const int* __restrict__ flags) {
  int f32 = flags[0];
  int ci = blockIdx.x;
  int rr = r0 + ci;
  __shared__ __align__(16) unsigned short F1h[64][72];
  __shared__ __align__(16) unsigned short F1l[64][72];
  int tid = threadIdx.x;
  int lane = tid & 63, wid = tid >> 6;
  int rlo = lane & 15, rhi = lane >> 4;
  size_t pcb = (size_t)ci * (2*DIM*DDIM);
  f32x4 zero = {0.f,0.f,0.f,0.f};
  // ---- dyn1: M=64(pad) N=64 K=256
  f32x4 acc1[4];
#pragma unroll
  for (int i = 0; i < 4; ++i) acc1[i] = zero;
  int s_a = 16*wid + rlo;
  int s_c = s_a > SS-1 ? SS-1 : s_a;       // clamp pad rows (finite garbage)
  for (int ks = 0; ks < 8; ++ks) {
    int k = ks*32 + rhi*8;
    short8 ah, al = (short8)0;
    if (!f32) {
      ah = *(const short8*)((const unsigned short*)roi + ((size_t)s_c*MTOT + rr)*DIM + k);
    } else {
      const float* rp = (const float*)roi + ((size_t)s_c*MTOT + rr)*DIM + k;
      float4 u0 = *(const float4*)rp, u1 = *(const float4*)(rp + 4);
      float v[8] = {u0.x,u0.y,u0.z,u0.w,u1.x,u1.y,u1.z,u1.w};
#pragma unroll
      for (int j = 0; j < 8; ++j) {
        unsigned short h = f2bfu(v[j]);
        ah[j] = (short)h;
        al[j] = (short)f2bfu(v[j] - bfu2f(h));
      }
    }
#pragma unroll
    for (int fn = 0; fn < 4; ++fn) {
      int e = fn*16 + rlo;
      short8 bh, bl;
      unpack8s(Ppk + pcb + (size_t)e*DIM + k, bh, bl);
      acc1[fn] = __builtin_amdgcn_mfma_f32_16x16x32_bf16(ah, bh, acc1[fn], 0, 0, 0);
      acc1[fn] = __builtin_amdgcn_mfma_f32_16x16x32_bf16(ah, bl, acc1[fn], 0, 0, 0);
      if (f32) acc1[fn] = __builtin_amdgcn_mfma_f32_16x16x32_bf16(al, bh, acc1[fn], 0, 0, 0);
    }
  }
  // ---- LN1 over e (64) + relu + split -> LDS
#pragma unroll
  for (int j = 0; j < 4; ++j) {
    float x[4], sum = 0.f;
#pragma unroll
    for (int fn = 0; fn < 4; ++fn) { x[fn] = acc1[fn][j]; sum += x[fn]; }
#pragma unroll
    for (int o = 8; o > 0; o >>= 1) sum += __shfl_xor(sum, o, 64);
    float mean = sum * (1.f/DDIM);
    float vs = 0.f;
#pragma unroll
    for (int fn = 0; fn < 4; ++fn) { float d0 = x[fn]-mean; vs += d0*d0; }
#pragma unroll
    for (int o = 8; o > 0; o >>= 1) vs += __shfl_xor(vs, o, 64);
    float rs = rsqrtf(vs*(1.f/DDIM) + 1e-5f);
    int row = 16*wid + rhi*4 + j;
#pragma unroll
    for (int fn = 0; fn < 4; ++fn) {
      float y = fmaxf((x[fn]-mean)*rs, 0.f);
      unsigned short h = f2bfu(y);
      F1h[row][fn*16 + rlo] = h;
      F1l[row][fn*16 + rlo] = f2bfu(y - bfu2f(h));
    }
  }
  __syncthreads();
  // ---- dyn2: M=64 N=256 K=64
  f32x4 acc2[16];
#pragma unroll
  for (int i = 0; i < 16; ++i) acc2[i] = zero;
  for (int ks = 0; ks < 2; ++ks) {
    int k = ks*32 + rhi*8;
    short8 ah = *(const short8*)&F1h[16*wid + rlo][k];
    short8 al = *(const short8*)&F1l[16*wid + rlo][k];
#pragma unroll
    for (int fn = 0; fn < 16; ++fn) {
      int d0 = fn*16 + rlo;
      short8 bh, bl;
      unpack8s(Ppk + pcb + DIM*DDIM + (size_t)d0*DDIM + k, bh, bl);
      acc2[fn] = __builtin_amdgcn_mfma_f32_16x16x32_bf16(ah, bh, acc2[fn], 0, 0, 0);
      acc2[fn] = __builtin_amdgcn_mfma_f32_16x16x32_bf16(al, bh, acc2[fn], 0, 0, 0);
      acc2[fn] = __builtin_amdgcn_mfma_f32_16x16x32_bf16(ah, bl, acc2[fn], 0, 0, 0);
    }
  }
  // ---- LN2 over d (256) + relu + packed write -> global f2
#pragma unroll
  for (int j = 0; j < 4; ++j) {
    float sum = 0.f;
#pragma unroll
    for (int fn = 0; fn < 16; ++fn) sum += acc2[fn][j];
#pragma unroll
    for (int o = 8; o > 0; o >>= 1) sum += __shfl_xor(sum, o, 64);
    float mean = sum * (1.f/DIM);
    float vs = 0.f;
#pragma unroll
    for (int fn = 0; fn < 16; ++fn) { float d0 = acc2[fn][j]-mean; vs += d0*d0; }
#pragma unroll
    for (int o = 8; o > 0; o >>= 1) vs += __shfl_xor(vs, o, 64);
    float rs = rsqrtf(vs*(1.f/DIM) + 1e-5f);
    int s = 16*wid + rhi*4 + j;
    if (s < SS) {
      size_t ob = ((size_t)ci*SS + s)*DIM;
#pragma unroll
      for (int fn = 0; fn < 16; ++fn) {
        float y = fmaxf((acc2[fn][j]-mean)*rs, 0.f);
        f2pk[ob + fn*16 + rlo] = packhl(y);
      }
    }
  }
}

// ---------------- normdyn ----------------
__global__ __launch_bounds__(256) void normdyn_kernel(const float* __restrict__ g,
                                                      const float* __restrict__ pf1,
                                                      float* __restrict__ pfB) {
  int r = blockIdx.x, t = threadIdx.x;
  __shared__ float s4[4];
  float x = g[(size_t)r*DIM + t];
  float mean = bsum(x, s4)*(1.f/DIM);
  float df = x - mean;
  float var = bsum(df*df, s4)*(1.f/DIM);
  float y = fmaxf(df*rsqrtf(var+1e-5f), 0.f);
  float x2 = pf1[(size_t)r*DIM + t] + y;
  float mean2 = bsum(x2, s4)*(1.f/DIM);
  float df2 = x2 - mean2;
  float var2 = bsum(df2*df2, s4)*(1.f/DIM);
  pfB[(size_t)r*DIM + t] = df2*rsqrtf(var2+1e-5f);
}

// ---------------- norm3 ----------------
__global__ __launch_bounds__(256) void norm3_kernel(const float* __restrict__ pfB,
                                                    const float* __restrict__ t2,
                                                    const void* __restrict__ mask,
                                                    float* __restrict__ fc,
                                                    const int* __restrict__ flags) {
  int f32 = flags[0];
  int r = blockIdx.x, t = threadIdx.x;
  __shared__ float s4[4];
  float x = pfB[(size_t)r*DIM + t] + t2[(size_t)r*DIM + t];
  float mean = bsum(x, s4)*(1.f/DIM);
  float df = x - mean;
  float var = bsum(df*df, s4)*(1.f/DIM);
  float y = df*rsqrtf(var+1e-5f);
  fc[(size_t)r*DIM + t] = y * ldv(mask, r, f32);
}

// ---------------- lncls ----------------
__global__ __launch_bounds__(256) void lncls_kernel(const float* __restrict__ g,
                                                    float* __restrict__ out) {
  int r = blockIdx.x, t = threadIdx.x;
  __shared__ float s4[4];
  float x = g[(size_t)r*DIM + t];
  float mean = bsum(x, s4)*(1.f/DIM);
  float df = x - mean;
  float var = bsum(df*df, s4)*(1.f/DIM);
  out[(size_t)r*DIM + t] = fmaxf(df*rsqrtf(var+1e-5f), 0.f);
}

// ---------------- final ----------------
__global__ __launch_bounds__(256) void final_kernel(const float* __restrict__ logf,
                                                    const int* __restrict__ flags,
                                                    void* __restrict__ out, int n) {
  int f32 = flags[0];
  int i = blockIdx.x*256 + threadIdx.x;
  if (i < n) {
    float v = logf[i];
    if (!(fabsf(v) <= 3.0e38f)) v = 0.f;
    if (i == 0) {
      int code = 0;
      for (int s = NFLAGS - 1; s >= 1; --s) if (flags[s]) code = 100 + 4*s;
      if (code) v = (float)code;
    }
    if (f32) ((float*)out)[i] = v;
    else ((bf16*)out)[i] = __float2bfloat16(v);
  }
}

extern "C" void kernel_launch(void* const* d_in, const int* in_sizes, int n_in,
                              void* d_out, int out_size, void* d_ws, size_t ws_size,
                              hipStream_t stream) {
  const void* bboxes     = d_in[0];
  const void* pro        = d_in[1];
  const void* roi        = d_in[2];
  const void* query      = d_in[3];
  const void* mask       = d_in[4];
  const void* w_qkv      = d_in[5];
  const void* b_qkv      = d_in[6];
  const void* w_attn_out = d_in[7];
  const void* b_attn_out = d_in[8];
  const void* w_dyn      = d_in[9];
  const void* b_dyn      = d_in[10];
  const void* w_dyn_out  = d_in[11];
  const void* b_dyn_out  = d_in[12];
  const void* w_ff1      = d_in[13];
  const void* b_ff1      = d_in[14];
  const void* w_ff2      = d_in[15];
  const void* b_ff2      = d_in[16];
  const void* w_cls      = d_in[17];
  const void* w_logits   = d_in[18];
  const void* b_logits   = d_in[19];
  (void)in_sizes; (void)n_in; (void)out_size;

  const size_t RD = (size_t)MTOT*DIM;

  // ---- workspace tiers; CHN capped at 600 so the dyn working set (Pc 78.6MB +
  //      roi slice + f2) stays L3-resident (256MB) — L3 blocking, not capacity. ----
  const size_t DYNROW = (size_t)2*DIM*DDIM;   // Pc: packed u32 == 1 float per param
  size_t wsf = ws_size / sizeof(float);
  size_t fixedf = 5*RD + (size_t)MTOT*NCLS + 256;
  auto spl_of = [&](size_t chn, size_t fh) {
    size_t a = chn*(size_t)SS*DIM, b = fh*(size_t)FFD;
    size_t m = a > b ? a : b; return m > RD ? m : RD;
  };
  auto need = [&](size_t chn, size_t fh) {
    return fixedf + chn*DYNROW + fh*FFD + spl_of(chn, fh);
  };
  int CHN = 64, FH = 300;
  if (wsf >= need(600, MTOT))       { CHN = 600;  FH = MTOT; }
  else if (wsf >= need(300, MTOT))  { CHN = 300;  FH = MTOT; }
  else if (wsf >= need(150, 300))   { CHN = 150;  FH = 300;  }
  const size_t SPL = spl_of(CHN, FH);

  float* Wsp = (float*)d_ws;
  size_t off = 0;
  auto alloc = [&](size_t n) { float* p = Wsp + off; off += n; return p; };
  float* A = alloc(RD);
  float* B = alloc(RD);
  float* C = alloc(RD);
  float* D = alloc(RD);
  float* E = alloc(RD);
  float* logf = alloc((size_t)MTOT*NCLS);
  float* ffh = alloc((size_t)FH*FFD);          // packed u32 for ffn hidden
  float* Pc  = alloc((size_t)CHN*2*DIM*DDIM);  // packed u32, permuted layout
  unsigned* Apk = (unsigned*)alloc(SPL + 8);
  int* flags = (int*)(Wsp + off);
  unsigned* ffpk = (unsigned*)ffh;
  unsigned* Ppk  = (unsigned*)Pc;

  dim3 b256(256);
  auto split = [&](const float* x, long long n) {
    long long n4 = n/4;
    split_kernel<<<(int)((n4 + 255)/256), b256, 0, stream>>>(x, Apk, n4);
  };
  auto gemm_full = [&](const unsigned* Apk_,
                       const void* Wm, long long woff,
                       const void* bias, long long boff, float* Cm,
                       unsigned* Cpk,
                       int M, int Nn, int K, int relu, int wperm) {
    int gm = (M + GBM - 1)/GBM;
    int gn = (Nn + GBN - 1)/GBN;
    int ntiles = K / GBK;
    int ks = 1;
    if (!relu && !Cpk && gm*gn < 512) {
      ks = (768 + gm*gn - 1)/(gm*gn);
      if (ks > ntiles) ks = ntiles;
    }
    int kit = (ntiles + ks - 1)/ks;
    ks = (ntiles + kit - 1)/kit;
    if (ks > 1) {
      int n = M*Nn;
      init_bias_kernel<<<(n + 255)/256, b256, 0, stream>>>(Cm, bias, boff, n, Nn, flags);
      gemm_mfma_k<<<dim3(gm, gn, ks), b256, 0, stream>>>(Apk_, Wm, woff, nullptr, 0,
                                                         Cm, nullptr,
                                                         M, Nn, K, relu, kit, 1, 0, flags);
    } else {
      gemm_mfma_k<<<dim3(gm, gn, 1), b256, 0, stream>>>(Apk_, Wm, woff, bias, boff,
                                                        Cm, Cpk,
                                                        M, Nn, K, relu, kit, 0, wperm, flags);
    }
  };
  auto gemm = [&](const unsigned* Apk_,
                  const void* Wm, long long woff,
                  const void* bias, long long boff, float* Cm,
                  int M, int Nn, int K, int relu) {
    gemm_full(Apk_, Wm, woff, bias, boff, Cm, nullptr, M, Nn, K, relu, 0);
  };

  zero_flags_kernel<<<1, 64, 0, stream>>>(flags);
  detect_dtype_kernel<<<256, b256, 0, stream>>>(w_qkv, 3LL*DIM*DIM, flags);

  prep_kernel<<<MTOT, b256, 0, stream>>>(pro, query, A, B, flags);  // A=pf0 B=qk
  split(B, RD);
  gemm(Apk, w_qkv, 0,                  b_qkv, 0,     C, MTOT, DIM, DIM, 0);  // C=qp
  gemm(Apk, w_qkv, (long long)DIM*DIM, b_qkv, DIM,   D, MTOT, DIM, DIM, 0);  // D=kp
  split(A, RD);
  gemm(Apk, w_qkv, 2LL*DIM*DIM,        b_qkv, 2*DIM, E, MTOT, DIM, DIM, 0);  // E=vp
  attn_kernel<<<MTOT, b256, 0, stream>>>(C, D, E, bboxes, mask, B, flags);   // B=ctx
  split(B, RD);
  gemm(Apk, w_attn_out, 0, b_attn_out, 0, C, MTOT, DIM, DIM, 0);             // C=tgt2
  norm1_kernel<<<MTOT, b256, 0, stream>>>(A, C, mask, D, flags);             // D=pf1

  for (int r0 = 0; r0 < MTOT; r0 += CHN) {
    int m = MTOT - r0 < CHN ? MTOT - r0 : CHN;
    split(D + (size_t)r0*DIM, (long long)m*DIM);
    // P-GEMM: permuted gather -> Ppk packed p1T/p2T, coalesced u32 writes (L3-resident)
    gemm_full(Apk, w_dyn, 0, b_dyn, 0, nullptr, Ppk, m, 2*DIM*DDIM, DIM, 0, 1);
    // fused MFMA dyn1+LN+relu+dyn2+LN+relu; writes packed f2 into Apk
    dyn_mfma_kernel<<<m, b256, 0, stream>>>(roi, Ppk, Apk, r0, flags);
    gemm(Apk, w_dyn_out, 0, b_dyn_out, 0, E + (size_t)r0*DIM,
         m, DIM, SS*DIM, 0);                                                 // E=gdyn
  }
  normdyn_kernel<<<MTOT, b256, 0, stream>>>(E, D, A);                        // A=pfB

  for (int r0 = 0; r0 < MTOT; r0 += FH) {
    int m = MTOT - r0 < FH ? MTOT - r0 : FH;
    split(A + (size_t)r0*DIM, (long long)m*DIM);
    gemm_full(Apk, w_ff1, 0, b_ff1, 0, nullptr, ffpk, m, FFD, DIM, 1, 0);    // hid packed
    gemm(ffpk, w_ff2, 0, b_ff2, 0, B + (size_t)r0*DIM, m, DIM, FFD, 0);      // B=t2
  }
  norm3_kernel<<<MTOT, b256, 0, stream>>>(A, B, mask, C, flags);             // C=fcb

  split(C, RD);
  gemm(Apk, w_cls, 0, nullptr, 0, D, MTOT, DIM, DIM, 0);                     // D=clsg
  lncls_kernel<<<MTOT, b256, 0, stream>>>(D, E);                             // E=clsf
  split(E, RD);
  gemm(Apk, w_logits, 0, b_logits, 0, logf, MTOT, NCLS, DIM, 0);

  final_kernel<<<((MTOT*NCLS)+255)/256, b256, 0, stream>>>(logf, flags, d_out, MTOT*NCLS);
}